// Round 1
// baseline (6392.340 us; speedup 1.0000x reference)
//
// FCGPFA variational iteration for MI355X (gfx950).
//
// Pipeline per launch (all on `stream`, graph-capture safe, deterministic):
//  S1 k_weights : direct 20-tap conv (thresholded in s-basis) + w_proj projection
//                 -> WA [m][t][n][l], WB [m][l][t][n], Yt [m][t][n]
//  S2 k_buildK  : Ktil = K + 1e-3*I, fp64, padded to 320 with identity
//  S3 k_chol<double,false> (1 WG)  : LK = chol(Ktil)
//  S4 k_diaginv<double> (10 WGs)   : 32x32 diag-block inverses of LK
//  S5 k_trtri<double> (1 WG)       : WK = LK^-1
//  S6 k_invK    : invK64 = WK^T WK, invK32 = fp32(invK64)
//  S7 k_EK,k_dh0: dh0 = diag(inv(invK32)) via 1st-order correction K~ - K~EK~
//  S8 k_init    : mu = 0, dh = dh0
//  iterate 5x:
//   I1 k_lambda : lam = exp(bias + w.(mu + 0.5 w dh))
//   I2 k_grad_d : grad = W^T(Y-lam) - invK.mu ; d = (W^2)^T lam
//   I3 k_chol<float,true> (128 WGs) : L = chol(invK32 + diag(d)) blocked nb=32
//   I4 k_diaginv<float> (1280 WGs)  : diag-block inverses (1 wave each)
//   I5 k_trtri<float> (128 WGs)     : W = L^-1 (row-block forward, reg-tiled)
//   I6 k_solve (128 WGs) : dh_next = -colsum(W^2); x = W^T W g (+1 fp64-residual
//                          refinement against exact A); mu += 0.5 x
//  F1 k_out    : transpose mu[m][t][l] -> out[m][l][t]
//
#include <hip/hip_runtime.h>
#include <math.h>

namespace {
constexpr int Mb   = 16;    // trials
constexpr int Nn   = 96;    // neurons
constexpr int NTF  = 350;   // full time
constexpr int Tt   = 300;   // sliced time
constexpr int NSUB = 8;
constexpr int NTAU = 20;
constexpr int NL   = 8;     // latents
constexpr int ML   = Mb * NL;   // 128 systems
constexpr int NP   = 320;   // padded matrix size (10 x 32)
constexpr int NB   = 32;
constexpr int NBLK = NP / NB;   // 10
constexpr int PTP  = 293;   // chol panel LDS stride
constexpr int LRP  = 296;   // trtri Lrow LDS stride
constexpr int TBW  = 160;   // trtri column chunk
}

__device__ __forceinline__ float  sqrt_(float x)  { return sqrtf(x); }
__device__ __forceinline__ double sqrt_(double x) { return sqrt(x); }

// wave-local LDS fence (single-wave synchronous sections)
__device__ __forceinline__ void lfence() {
  asm volatile("s_waitcnt lgkmcnt(0)" ::: "memory");
}

// ---------------------------------------------------------------- S1: weights
__global__ __launch_bounds__(256) void k_weights(
    const float* __restrict__ Yraw, const float* __restrict__ kern,
    const float* __restrict__ wproj, float* __restrict__ WA,
    float* __restrict__ WB, float* __restrict__ Yt) {
  __shared__ float sk[NTAU * NSUB];
  __shared__ float sp[NSUB * NL];
  const int tid = threadIdx.x;
  if (tid < NTAU * NSUB) sk[tid] = kern[tid];
  if (tid < NSUB * NL)   sp[tid] = wproj[tid];
  __syncthreads();
  const int g = blockIdx.x * 256 + tid;            // g = (m*Tt + t)*Nn + n
  if (g >= Mb * Tt * Nn) return;
  const int n  = g % Nn;
  const int mt = g / Nn;
  const int t  = mt % Tt;
  const int m  = mt / Tt;
  const float* yr = Yraw + ((size_t)m * Nn + n) * NTF + 30 + t;
  float ya[NTAU + 1];
#pragma unroll
  for (int j = 0; j <= NTAU; ++j) ya[j] = yr[j];
  float gs[NSUB];
#pragma unroll
  for (int s = 0; s < NSUB; ++s) {
    float acc = 0.f;
#pragma unroll
    for (int j = 0; j < NTAU; ++j) acc += ya[j] * sk[(NTAU - 1 - j) * NSUB + s];
    gs[s] = (fabsf(acc) < 1e-5f) ? 0.f : acc;      // reference threshold
  }
  float w[NL];
#pragma unroll
  for (int l = 0; l < NL; ++l) {
    float acc = 0.f;
#pragma unroll
    for (int s = 0; s < NSUB; ++s) acc += gs[s] * sp[s * NL + l];
    w[l] = acc;
  }
  float4* wa4 = reinterpret_cast<float4*>(WA + (size_t)g * NL);
  wa4[0] = make_float4(w[0], w[1], w[2], w[3]);
  wa4[1] = make_float4(w[4], w[5], w[6], w[7]);
#pragma unroll
  for (int l = 0; l < NL; ++l)
    WB[(((size_t)m * NL + l) * Tt + t) * Nn + n] = w[l];
  Yt[g] = ya[NTAU];                                // Yraw[m][n][50+t]
}

// ---------------------------------------------------------------- S2: K tilde
__global__ __launch_bounds__(256) void k_buildK(
    const float* __restrict__ K, double* __restrict__ Kt, double* __restrict__ Kw) {
  const int g = blockIdx.x * 256 + threadIdx.x;
  if (g >= NP * NP) return;
  const int j = g % NP, i = g / NP;
  double v;
  if (i < Tt && j < Tt) { v = (double)K[i * Tt + j]; if (i == j) v += 1e-3; }
  else v = (i == j) ? 1.0 : 0.0;
  Kt[g] = v; Kw[g] = v;
}

// --------------------------------------------------- blocked Cholesky (in place)
template <typename T, bool INIT>
__global__ __launch_bounds__(512) void k_chol(
    T* __restrict__ Ab, const float* __restrict__ invK, const float* __restrict__ dvec) {
  const int id = blockIdx.x;
  T* A = Ab + (size_t)id * NP * NP;
  const int tid = threadIdx.x;
  __shared__ T Dl[NB][NB + 1];   // diag block (+1 col holds 1/pivot)
  __shared__ T PT[NB][PTP];      // panel transposed: PT[p][row - r0]
  if constexpr (INIT) {
    const float* dv = dvec + (size_t)id * Tt;
    for (int e = tid; e < NP * NP; e += 512) {
      const int i = e / NP, j = e - i * NP;
      float v = invK[e];
      if (i == j && i < Tt) v += dv[i];
      A[e] = (T)v;
    }
    __syncthreads();
  }
  for (int pb = 0; pb < NBLK; ++pb) {
    const int j0 = pb * NB;
    const int r0 = j0 + NB;
    const int Mrem = NP - r0;
    // stage diag block
    for (int e = tid; e < NB * NB; e += 512) {
      const int r = e / NB, c = e - r * NB;
      Dl[r][c] = (c <= r) ? A[(size_t)(j0 + r) * NP + (j0 + c)] : (T)0;
    }
    __syncthreads();
    // wave-synchronous 32x32 mini-Cholesky (wave 0 only)
    if (tid < 64) {
      for (int c = 0; c < NB; ++c) {
        if (tid == 0) {
          T s = sqrt_(Dl[c][c]);
          Dl[c][c] = s;
          Dl[c][NB] = (T)1 / s;
        }
        lfence();
        const T cinv = Dl[c][NB];
        if (tid > c && tid < NB) Dl[tid][c] *= cinv;
        lfence();
        const int w = NB - 1 - c;
        for (int e = tid; e < w * w; e += 64) {
          const int r = c + 1 + e / w;
          const int k = c + 1 + e % w;
          Dl[r][k] -= Dl[r][c] * Dl[k][c];
        }
        lfence();
      }
    }
    __syncthreads();
    // write diag block back
    for (int e = tid; e < NB * NB; e += 512) {
      const int r = e / NB, c = e - r * NB;
      if (c <= r) A[(size_t)(j0 + r) * NP + (j0 + c)] = Dl[r][c];
    }
    if (Mrem > 0) {
      // panel solve: row i (below diag):  v <- v * D^-T  (forward in c)
      for (int i = r0 + tid; i < NP; i += 512) {
        T v[NB];
#pragma unroll
        for (int c = 0; c < NB; ++c) v[c] = A[(size_t)i * NP + j0 + c];
#pragma unroll
        for (int c = 0; c < NB; ++c) {
          T acc = v[c];
          for (int k = 0; k < c; ++k) acc -= v[k] * Dl[c][k];
          v[c] = acc * Dl[c][NB];
        }
        const int ri = i - r0;
#pragma unroll
        for (int c = 0; c < NB; ++c) {
          A[(size_t)i * NP + j0 + c] = v[c];
          PT[c][ri] = v[c];
        }
      }
      __syncthreads();
      // trailing update, 8x8 register tiles over lower triangle
      const int nt = Mrem / 8;
      const int ntile = nt * (nt + 1) / 2;
      for (int tix = tid; tix < ntile; tix += 512) {
        int ti = (int)((sqrtf(8.0f * (float)tix + 1.0f) - 1.0f) * 0.5f);
        while ((ti + 1) * (ti + 2) / 2 <= tix) ++ti;
        while (ti * (ti + 1) / 2 > tix) --ti;
        const int tj = tix - ti * (ti + 1) / 2;
        const int ri = r0 + ti * 8, rj = r0 + tj * 8;
        T acc[8][8];
#pragma unroll
        for (int r = 0; r < 8; ++r)
#pragma unroll
          for (int c = 0; c < 8; ++c) acc[r][c] = (T)0;
        for (int p = 0; p < NB; ++p) {
          T a[8], b[8];
#pragma unroll
          for (int r = 0; r < 8; ++r) a[r] = PT[p][ti * 8 + r];
#pragma unroll
          for (int c = 0; c < 8; ++c) b[c] = PT[p][tj * 8 + c];
#pragma unroll
          for (int r = 0; r < 8; ++r)
#pragma unroll
            for (int c = 0; c < 8; ++c) acc[r][c] += a[r] * b[c];
        }
#pragma unroll
        for (int r = 0; r < 8; ++r)
#pragma unroll
          for (int c = 0; c < 8; ++c)
            A[(size_t)(ri + r) * NP + (rj + c)] -= acc[r][c];
      }
      __syncthreads();
    }
  }
}

// ------------------------------------------ 32x32 diag-block inverses (1 wave)
template <typename T>
__global__ __launch_bounds__(64) void k_diaginv(
    const T* __restrict__ Lb, T* __restrict__ Dinv) {
  const int b = blockIdx.x % NBLK;
  const int mat = blockIdx.x / NBLK;
  const T* A = Lb + (size_t)mat * NP * NP + (size_t)(b * NB) * NP + b * NB;
  __shared__ T D[NB][NB + 1];
  __shared__ T V[NB][NB + 1];
  const int tid = threadIdx.x;
  for (int e = tid; e < NB * (NB + 1); e += 64) (&V[0][0])[e] = (T)0;
  for (int e = tid; e < NB * NB; e += 64) {
    const int r = e / NB, c = e - r * NB;
    D[r][c] = (c <= r) ? A[(size_t)r * NP + c] : (T)0;
  }
  __syncthreads();
  if (tid < NB) {               // lane c computes column c of D^-1 (lane-private)
    const int c = tid;
    V[c][c] = (T)1 / D[c][c];
    for (int r = c + 1; r < NB; ++r) {
      T acc = (T)0;
      for (int k = c; k < r; ++k) acc += D[r][k] * V[k][c];
      V[r][c] = -acc / D[r][r];
    }
  }
  __syncthreads();
  for (int e = tid; e < NB * NB; e += 64) {
    const int r = e / NB, c = e - r * NB;
    Dinv[(size_t)blockIdx.x * NB * NB + e] = V[r][c];
  }
}

// -------------------------- W = L^-1, row-block forward sweep, reg-tiled 4x4
template <typename T>
__global__ __launch_bounds__(512) void k_trtri(
    const T* __restrict__ Lb, T* __restrict__ Wb, const T* __restrict__ Dinv) {
  const int mat = blockIdx.x;
  const T* L = Lb + (size_t)mat * NP * NP;
  T* W = Wb + (size_t)mat * NP * NP;
  const T* Dv = Dinv + (size_t)mat * NBLK * NB * NB;
  const int tid = threadIdx.x;
  __shared__ T Lrow[NB][LRP];
  __shared__ T Di[NB][NB + 1];
  __shared__ T Tb[NB][TBW + 4];
  for (int I = 0; I < NBLK; ++I) {
    const int ccols = I * NB;
    for (int e = tid; e < NB * NB; e += 512) {      // diag block = Dinv_I
      const T v = Dv[(size_t)I * NB * NB + e];
      Di[e / NB][e % NB] = v;
      W[(size_t)(I * NB + e / NB) * NP + I * NB + (e % NB)] = v;
    }
    for (int e = tid; e < NB * ccols; e += 512) {
      const int r = e / ccols, c = e - r * ccols;
      Lrow[r][c] = L[(size_t)(I * NB + r) * NP + c];
    }
    __syncthreads();
    for (int c0 = 0; c0 < ccols; c0 += TBW) {
      const int cw = (ccols - c0 < TBW) ? (ccols - c0) : TBW;
      const int ntc = cw / 4, ntr = NB / 4;
      // phase 1: Tb = -sum_K L[I][K] * W[K][J]
      for (int tix = tid; tix < ntr * ntc; tix += 512) {
        const int tr = tix / ntc, tc = tix - (tix / ntc) * ntc;
        const int cc = c0 + tc * 4;
        const int Jblk = cc / NB;
        T acc[4][4];
#pragma unroll
        for (int r = 0; r < 4; ++r)
#pragma unroll
          for (int c = 0; c < 4; ++c) acc[r][c] = (T)0;
        for (int kk = Jblk * NB; kk < ccols; ++kk) {
          const T* wr = &W[(size_t)kk * NP + cc];
          const T b0 = wr[0], b1 = wr[1], b2 = wr[2], b3 = wr[3];
#pragma unroll
          for (int r = 0; r < 4; ++r) {
            const T a = Lrow[tr * 4 + r][kk];
            acc[r][0] += a * b0; acc[r][1] += a * b1;
            acc[r][2] += a * b2; acc[r][3] += a * b3;
          }
        }
#pragma unroll
        for (int r = 0; r < 4; ++r)
#pragma unroll
          for (int c = 0; c < 4; ++c) Tb[tr * 4 + r][tc * 4 + c] = -acc[r][c];
      }
      __syncthreads();
      // phase 2: W[I][J] = Di * Tb
      for (int tix = tid; tix < ntr * ntc; tix += 512) {
        const int tr = tix / ntc, tc = tix - (tix / ntc) * ntc;
        T acc[4][4];
#pragma unroll
        for (int r = 0; r < 4; ++r)
#pragma unroll
          for (int c = 0; c < 4; ++c) acc[r][c] = (T)0;
        for (int k = 0; k < NB; ++k) {
          const T t0 = Tb[k][tc * 4 + 0], t1 = Tb[k][tc * 4 + 1];
          const T t2 = Tb[k][tc * 4 + 2], t3 = Tb[k][tc * 4 + 3];
#pragma unroll
          for (int r = 0; r < 4; ++r) {
            const T d = Di[tr * 4 + r][k];
            acc[r][0] += d * t0; acc[r][1] += d * t1;
            acc[r][2] += d * t2; acc[r][3] += d * t3;
          }
        }
#pragma unroll
        for (int r = 0; r < 4; ++r)
#pragma unroll
          for (int c = 0; c < 4; ++c)
            W[(size_t)(I * NB + tr * 4 + r) * NP + c0 + tc * 4 + c] = acc[r][c];
      }
      __syncthreads();
    }
  }
}

// --------------------------------------------------- S6: invK = WK^T WK (fp64)
__global__ __launch_bounds__(256) void k_invK(
    const double* __restrict__ WK, double* __restrict__ invK64, float* __restrict__ invK32) {
  const int g = blockIdx.x * 256 + threadIdx.x;
  if (g >= NP * NP) return;
  const int j = g % NP, i = g / NP;
  const int k0 = (i > j) ? i : j;
  double acc = 0.0;
  for (int k = k0; k < NP; ++k) acc += WK[(size_t)k * NP + i] * WK[(size_t)k * NP + j];
  invK64[g] = acc;
  invK32[g] = (float)acc;
}

// ------------------------- S7: dh0 = diag(inv(invK32)) ~= diag(Kt - Kt*E*Kt)
__global__ __launch_bounds__(256) void k_EK(
    const float* __restrict__ invK32, const double* __restrict__ invK64,
    const double* __restrict__ Kt, double* __restrict__ M1) {
  const int g = blockIdx.x * 256 + threadIdx.x;
  if (g >= NP * NP) return;
  const int j = g % NP, i = g / NP;
  double acc = 0.0;
  for (int s = 0; s < NP; ++s) {
    const double e = (double)invK32[(size_t)i * NP + s] - invK64[(size_t)i * NP + s];
    acc += e * Kt[(size_t)s * NP + j];
  }
  M1[g] = acc;
}

__global__ __launch_bounds__(320) void k_dh0(
    const double* __restrict__ Kt, const double* __restrict__ M1, float* __restrict__ dh0) {
  const int t = threadIdx.x;
  if (t >= Tt) return;
  double acc = 0.0;
  for (int s = 0; s < NP; ++s) acc += Kt[(size_t)t * NP + s] * M1[(size_t)s * NP + t];
  dh0[t] = (float)(Kt[(size_t)t * NP + t] - acc);
}

__global__ __launch_bounds__(256) void k_init(
    const float* __restrict__ dh0, float* __restrict__ mu, float* __restrict__ dh) {
  const int g = blockIdx.x * 256 + threadIdx.x;
  if (g >= Mb * Tt * NL) return;
  mu[g] = 0.f;
  dh[g] = dh0[(g / NL) % Tt];
}

// ---------------------------------------------------------------- I1: lambda
__global__ __launch_bounds__(256) void k_lambda(
    const float* __restrict__ WA, const float* __restrict__ mu,
    const float* __restrict__ dh, const float* __restrict__ biasp,
    float* __restrict__ lam) {
  const int g = blockIdx.x * 256 + threadIdx.x;
  if (g >= Mb * Tt * Nn) return;
  const int mt = g / Nn;
  const float b = biasp[0];
  const float4* wa = reinterpret_cast<const float4*>(WA + (size_t)g * NL);
  const float4* mp = reinterpret_cast<const float4*>(mu + (size_t)mt * NL);
  const float4* dp = reinterpret_cast<const float4*>(dh + (size_t)mt * NL);
  const float4 w0 = wa[0], w1 = wa[1];
  const float4 m0 = mp[0], m1 = mp[1];
  const float4 h0 = dp[0], h1 = dp[1];
  float e = b;
  e += w0.x * (m0.x + 0.5f * w0.x * h0.x);
  e += w0.y * (m0.y + 0.5f * w0.y * h0.y);
  e += w0.z * (m0.z + 0.5f * w0.z * h0.z);
  e += w0.w * (m0.w + 0.5f * w0.w * h0.w);
  e += w1.x * (m1.x + 0.5f * w1.x * h1.x);
  e += w1.y * (m1.y + 0.5f * w1.y * h1.y);
  e += w1.z * (m1.z + 0.5f * w1.z * h1.z);
  e += w1.w * (m1.w + 0.5f * w1.w * h1.w);
  lam[g] = expf(e);
}

// ---------------------------------------------------------------- I2: grad, d
__global__ __launch_bounds__(320) void k_grad_d(
    const float* __restrict__ WB, const float* __restrict__ Yt,
    const float* __restrict__ lam, const float* __restrict__ invK32,
    const float* __restrict__ mu, float* __restrict__ grad, float* __restrict__ dvec) {
  const int ml = blockIdx.x;
  const int m = ml / NL, l = ml % NL;
  const int t = threadIdx.x;
  __shared__ float mus[NP];
  mus[t] = (t < Tt) ? mu[((size_t)m * Tt + t) * NL + l] : 0.f;
  __syncthreads();
  float g1 = 0.f, dd = 0.f;
  if (t < Tt) {
    const float4* wb = reinterpret_cast<const float4*>(WB + ((size_t)ml * Tt + t) * Nn);
    const float4* yt = reinterpret_cast<const float4*>(Yt + ((size_t)m * Tt + t) * Nn);
    const float4* la = reinterpret_cast<const float4*>(lam + ((size_t)m * Tt + t) * Nn);
    for (int q = 0; q < Nn / 4; ++q) {
      const float4 w = wb[q], y = yt[q], v = la[q];
      g1 += w.x * (y.x - v.x) + w.y * (y.y - v.y) + w.z * (y.z - v.z) + w.w * (y.w - v.w);
      dd += w.x * w.x * v.x + w.y * w.y * v.y + w.z * w.z * v.z + w.w * w.w * v.w;
    }
  }
  float g2 = 0.f;
  for (int s = 0; s < Tt; ++s)                   // invK symmetric: coalesced rows
    g2 += invK32[(size_t)s * NP + t] * mus[s];
  if (t < Tt) {
    grad[(size_t)ml * Tt + t] = g1 - g2;
    dvec[(size_t)ml * Tt + t] = dd;
  }
}

// ------------------------------- I6: dh = -colsum(W^2); mu += 0.5 * A^-1 grad
__global__ __launch_bounds__(320) void k_solve(
    const float* __restrict__ Wb, const float* __restrict__ invK32,
    const float* __restrict__ grad, const float* __restrict__ dvec,
    float* __restrict__ mu, float* __restrict__ dh) {
  const int ml = blockIdx.x;
  const int m = ml / NL, l = ml % NL;
  const float* W = Wb + (size_t)ml * NP * NP;
  const int t = threadIdx.x;                     // 0..319
  __shared__ float  gs[NP];
  __shared__ float  Wblk[NB][NP + 13];
  __shared__ float  part[NB][11];
  __shared__ double partd[NB][11];
  __shared__ float  zv[NB];
  __shared__ double xs[NP];
  __shared__ double rs[NP];
  gs[t] = (t < Tt) ? grad[(size_t)ml * Tt + t] : 0.f;
  __syncthreads();
  float yacc = 0.f, dhacc = 0.f;
  // pass 1: x0 = W^T W g  (+ dh colsums)
  for (int I = 0; I < NBLK; ++I) {
    for (int e = t; e < NB * NP; e += 320)
      Wblk[e / NP][e % NP] = W[(size_t)(I * NB + e / NP) * NP + (e % NP)];
    __syncthreads();
    {
      const int r = t & 31, c = t >> 5;
      float p = 0.f;
      if (c <= I) {
        const int k0 = c * NB;
        for (int k = 0; k < NB; ++k) p += Wblk[r][k0 + k] * gs[k0 + k];
      }
      part[r][c] = p;
    }
    __syncthreads();
    if (t < NB) {
      float z = 0.f;
      for (int c = 0; c <= I; ++c) z += part[t][c];
      zv[t] = z;
    }
    __syncthreads();
    if (t < (I + 1) * NB) {
      float ya = 0.f, dha = 0.f;
      for (int r = 0; r < NB; ++r) {
        const float w = Wblk[r][t];
        ya += w * zv[r];
        dha += w * w;
      }
      yacc += ya; dhacc += dha;
    }
    __syncthreads();
  }
  xs[t] = (double)yacc;
  __syncthreads();
  // pass 2: fp64 residual r = g - (invK + diag(d)) x
  for (int I = 0; I < NBLK; ++I) {
    for (int e = t; e < NB * NP; e += 320)
      Wblk[e / NP][e % NP] = invK32[(size_t)(I * NB + e / NP) * NP + (e % NP)];
    __syncthreads();
    {
      const int r = t & 31, c = t >> 5;
      double p = 0.0;
      const int k0 = c * NB;
      for (int k = 0; k < NB; ++k) p += (double)Wblk[r][k0 + k] * xs[k0 + k];
      partd[r][c] = p;
    }
    __syncthreads();
    if (t < NB) {
      double av = 0.0;
      for (int c = 0; c < NBLK; ++c) av += partd[t][c];
      const int row = I * NB + t;
      const double dterm = (row < Tt) ? (double)dvec[(size_t)ml * Tt + row] * xs[row] : 0.0;
      rs[row] = (double)gs[row] - av - dterm;
    }
    __syncthreads();
  }
  // pass 3: delta = W^T W r ; x += delta
  gs[t] = (float)rs[t];
  __syncthreads();
  float y2 = 0.f;
  for (int I = 0; I < NBLK; ++I) {
    for (int e = t; e < NB * NP; e += 320)
      Wblk[e / NP][e % NP] = W[(size_t)(I * NB + e / NP) * NP + (e % NP)];
    __syncthreads();
    {
      const int r = t & 31, c = t >> 5;
      float p = 0.f;
      if (c <= I) {
        const int k0 = c * NB;
        for (int k = 0; k < NB; ++k) p += Wblk[r][k0 + k] * gs[k0 + k];
      }
      part[r][c] = p;
    }
    __syncthreads();
    if (t < NB) {
      float z = 0.f;
      for (int c = 0; c <= I; ++c) z += part[t][c];
      zv[t] = z;
    }
    __syncthreads();
    if (t < (I + 1) * NB) {
      float ya = 0.f;
      for (int r = 0; r < NB; ++r) ya += Wblk[r][t] * zv[r];
      y2 += ya;
    }
    __syncthreads();
  }
  xs[t] += (double)y2;
  if (t < Tt) {
    const size_t idx = ((size_t)m * Tt + t) * NL + l;
    mu[idx] = mu[idx] + (float)(0.5 * xs[t]);     // LR = 0.5, mu += LR * A^-1 g
    dh[idx] = -dhacc;                             // dh for next iteration
  }
}

// ---------------------------------------------------------------- F1: output
__global__ __launch_bounds__(256) void k_out(
    const float* __restrict__ mu, float* __restrict__ out) {
  const int g = blockIdx.x * 256 + threadIdx.x;   // g = (m*NL + l)*Tt + t
  if (g >= Mb * NL * Tt) return;
  const int t = g % Tt;
  const int ml = g / Tt;
  const int m = ml / NL, l = ml % NL;
  out[g] = mu[((size_t)m * Tt + t) * NL + l];
}

// ------------------------------------------------------------------- launcher
extern "C" void kernel_launch(void* const* d_in, const int* in_sizes, int n_in,
                              void* d_out, int out_size, void* d_ws, size_t ws_size,
                              hipStream_t stream) {
  (void)in_sizes; (void)n_in; (void)out_size;
  const float* Yraw  = (const float*)d_in[0];
  const float* kern  = (const float*)d_in[1];
  const float* wproj = (const float*)d_in[2];
  const float* K     = (const float*)d_in[3];
  const float* biasp = (const float*)d_in[4];
  float* out = (float*)d_out;

  char* base = (char*)d_ws;
  size_t off = 0;
  auto alloc = [&](size_t bytes) -> void* {
    void* p = base + off;
    off += (bytes + 511) & ~(size_t)511;
    return p;
  };
  float*  WA     = (float*) alloc((size_t)Mb * Tt * Nn * NL * 4);
  float*  WB     = (float*) alloc((size_t)Mb * Tt * Nn * NL * 4);
  float*  Yt     = (float*) alloc((size_t)Mb * Tt * Nn * 4);
  float*  lam    = (float*) alloc((size_t)Mb * Tt * Nn * 4);
  float*  mu     = (float*) alloc((size_t)Mb * Tt * NL * 4);
  float*  dh     = (float*) alloc((size_t)Mb * Tt * NL * 4);
  float*  grad   = (float*) alloc((size_t)ML * Tt * 4);
  float*  dvec   = (float*) alloc((size_t)ML * Tt * 4);
  float*  Lbuf   = (float*) alloc((size_t)ML * NP * NP * 4);
  float*  Wbuf   = (float*) alloc((size_t)ML * NP * NP * 4);
  float*  DinvF  = (float*) alloc((size_t)ML * NBLK * NB * NB * 4);
  float*  invK32 = (float*) alloc((size_t)NP * NP * 4);
  double* Kt64   = (double*)alloc((size_t)NP * NP * 8);
  double* Kwork  = (double*)alloc((size_t)NP * NP * 8);
  double* WK64   = (double*)alloc((size_t)NP * NP * 8);
  double* invK64 = (double*)alloc((size_t)NP * NP * 8);
  double* M1     = (double*)alloc((size_t)NP * NP * 8);
  double* Dinv64 = (double*)alloc((size_t)NBLK * NB * NB * 8);
  float*  dh0    = (float*) alloc((size_t)NP * 4);
  if (off > ws_size) return;   // workspace too small -> visible as wrong output

  const int gMTN = (Mb * Tt * Nn) / 256;     // 1800
  const int gNP2 = (NP * NP + 255) / 256;    // 400
  const int gMTL = (Mb * Tt * NL + 255) / 256; // 150

  // setup
  k_weights<<<gMTN, 256, 0, stream>>>(Yraw, kern, wproj, WA, WB, Yt);
  k_buildK<<<gNP2, 256, 0, stream>>>(K, Kt64, Kwork);
  k_chol<double, false><<<1, 512, 0, stream>>>(Kwork, nullptr, nullptr);
  k_diaginv<double><<<NBLK, 64, 0, stream>>>(Kwork, Dinv64);
  k_trtri<double><<<1, 512, 0, stream>>>(Kwork, WK64, Dinv64);
  k_invK<<<gNP2, 256, 0, stream>>>(WK64, invK64, invK32);
  k_EK<<<gNP2, 256, 0, stream>>>(invK32, invK64, Kt64, M1);
  k_dh0<<<1, 320, 0, stream>>>(Kt64, M1, dh0);
  k_init<<<gMTL, 256, 0, stream>>>(dh0, mu, dh);

  // 5 VI iterations
  for (int it = 0; it < 5; ++it) {
    k_lambda<<<gMTN, 256, 0, stream>>>(WA, mu, dh, biasp, lam);
    k_grad_d<<<ML, 320, 0, stream>>>(WB, Yt, lam, invK32, mu, grad, dvec);
    k_chol<float, true><<<ML, 512, 0, stream>>>(Lbuf, invK32, dvec);
    k_diaginv<float><<<ML * NBLK, 64, 0, stream>>>(Lbuf, DinvF);
    k_trtri<float><<<ML, 512, 0, stream>>>(Lbuf, Wbuf, DinvF);
    k_solve<<<ML, 320, 0, stream>>>(Wbuf, invK32, grad, dvec, mu, dh);
  }
  k_out<<<gMTL, 256, 0, stream>>>(mu, out);
}

// Round 2
// 4001.926 us; speedup vs baseline: 1.5973x; 1.5973x over previous
//
// FCGPFA variational iteration for MI355X (gfx950). Round 2.
//
//  S1 k_weights : direct 20-tap conv (thresholded in s-basis) + w_proj projection
//  S2 k_buildK  : Ktil = K + 1e-3*I, fp64, padded to 320 with identity
//  S3 k_chol<double,false> (1 WG)  : LK = chol(Ktil) + fused diag-block inverses
//  S4 k_trtri2<double> (10 WGs)    : WK = LK^-1, column-block-parallel
//  S5 k_invK    : invK64 = WK^T WK, invK32 = fp32(invK64)
//  S6 k_EK,k_dh0: dh0 = diag(inv(invK32)) via 1st-order correction K~ - K~EK~
//  S7 k_init    : mu = 0, dh = dh0
//  iterate 5x:
//   I1 k_lambda : lam = exp(bias + w.(mu + 0.5 w dh))
//   I2 k_grad_d : grad = W^T(Y-lam) - invK.mu ; d = (W^2)^T lam
//   I3 k_chol<float,true> (128 WGs): L = chol(invK32 + diag(d)) + fused diaginv
//   I4 k_trtri2<float> (1280 WGs)  : W = L^-1 column-block-parallel
//   I5 k_solve (128 WGs) : dh_next = -colsum(W^2); mu += 0.5*(W^T W g + fp64-
//                          residual refinement)
//  F1 k_out    : transpose mu[m][t][l] -> out[m][l][t]
//
#include <hip/hip_runtime.h>
#include <math.h>

namespace {
constexpr int Mb   = 16;    // trials
constexpr int Nn   = 96;    // neurons
constexpr int NTF  = 350;   // full time
constexpr int Tt   = 300;   // sliced time
constexpr int NSUB = 8;
constexpr int NTAU = 20;
constexpr int NL   = 8;     // latents
constexpr int ML   = Mb * NL;   // 128 systems
constexpr int NP   = 320;   // padded matrix size (10 x 32)
constexpr int NB   = 32;
constexpr int NBLK = NP / NB;   // 10
constexpr int PTS  = 292;   // PTc row stride: %4==0 (b128 aligned), %32==4 (bank spread)
}

__device__ __forceinline__ float  sqrt_(float x)  { return sqrtf(x); }
__device__ __forceinline__ double sqrt_(double x) { return sqrt(x); }

// wave-local LDS fence (single-wave synchronous sections)
__device__ __forceinline__ void lfence() {
  asm volatile("s_waitcnt lgkmcnt(0)" ::: "memory");
}

// ---------------------------------------------------------------- S1: weights
__global__ __launch_bounds__(256) void k_weights(
    const float* __restrict__ Yraw, const float* __restrict__ kern,
    const float* __restrict__ wproj, float* __restrict__ WA,
    float* __restrict__ WB, float* __restrict__ Yt) {
  __shared__ float sk[NTAU * NSUB];
  __shared__ float sp[NSUB * NL];
  const int tid = threadIdx.x;
  if (tid < NTAU * NSUB) sk[tid] = kern[tid];
  if (tid < NSUB * NL)   sp[tid] = wproj[tid];
  __syncthreads();
  const int g = blockIdx.x * 256 + tid;            // g = (m*Tt + t)*Nn + n
  if (g >= Mb * Tt * Nn) return;
  const int n  = g % Nn;
  const int mt = g / Nn;
  const int t  = mt % Tt;
  const int m  = mt / Tt;
  const float* yr = Yraw + ((size_t)m * Nn + n) * NTF + 30 + t;
  float ya[NTAU + 1];
#pragma unroll
  for (int j = 0; j <= NTAU; ++j) ya[j] = yr[j];
  float gs[NSUB];
#pragma unroll
  for (int s = 0; s < NSUB; ++s) {
    float acc = 0.f;
#pragma unroll
    for (int j = 0; j < NTAU; ++j) acc += ya[j] * sk[(NTAU - 1 - j) * NSUB + s];
    gs[s] = (fabsf(acc) < 1e-5f) ? 0.f : acc;      // reference threshold
  }
  float w[NL];
#pragma unroll
  for (int l = 0; l < NL; ++l) {
    float acc = 0.f;
#pragma unroll
    for (int s = 0; s < NSUB; ++s) acc += gs[s] * sp[s * NL + l];
    w[l] = acc;
  }
  float4* wa4 = reinterpret_cast<float4*>(WA + (size_t)g * NL);
  wa4[0] = make_float4(w[0], w[1], w[2], w[3]);
  wa4[1] = make_float4(w[4], w[5], w[6], w[7]);
#pragma unroll
  for (int l = 0; l < NL; ++l)
    WB[(((size_t)m * NL + l) * Tt + t) * Nn + n] = w[l];
  Yt[g] = ya[NTAU];                                // Yraw[m][n][50+t]
}

// ---------------------------------------------------------------- S2: K tilde
__global__ __launch_bounds__(256) void k_buildK(
    const float* __restrict__ K, double* __restrict__ Kt, double* __restrict__ Kw) {
  const int g = blockIdx.x * 256 + threadIdx.x;
  if (g >= NP * NP) return;
  const int j = g % NP, i = g / NP;
  double v;
  if (i < Tt && j < Tt) { v = (double)K[i * Tt + j]; if (i == j) v += 1e-3; }
  else v = (i == j) ? 1.0 : 0.0;
  Kt[g] = v; Kw[g] = v;
}

// ---------------- blocked Cholesky (in place, lower) + fused diag-block inverse
template <typename T, bool INIT>
__global__ __launch_bounds__(512) void k_chol(
    T* __restrict__ Ab, const float* __restrict__ invK,
    const float* __restrict__ dvec, T* __restrict__ Dinv) {
  const int id = blockIdx.x;
  T* A = Ab + (size_t)id * NP * NP;
  const int tid = threadIdx.x;
  __shared__ T Dl[NB][NB + 1];    // diag block (+1 col holds 1/pivot)
  __shared__ T PTc[36][PTS];      // panel, chunk-transposed: PTc[ri/8][8*p + ri%8]
  if constexpr (INIT) {
    const float* dv = dvec + (size_t)id * Tt;
    for (int e = tid; e < NP * NP; e += 512) {
      const int i = e / NP, j = e - i * NP;
      if (j > i) continue;                          // lower triangle only
      float v = invK[e];
      if (i == j && i < Tt) v += dv[i];
      A[e] = (T)v;
    }
    __syncthreads();
  }
  for (int pb = 0; pb < NBLK; ++pb) {
    const int j0 = pb * NB;
    const int r0 = j0 + NB;
    const int Mrem = NP - r0;
    // stage diag block
    for (int e = tid; e < NB * NB; e += 512) {
      const int r = e / NB, c = e - r * NB;
      Dl[r][c] = (c <= r) ? A[(size_t)(j0 + r) * NP + (j0 + c)] : (T)0;
    }
    __syncthreads();
    // wave-synchronous 32x32 mini-Cholesky (wave 0 only)
    if (tid < 64) {
      for (int c = 0; c < NB; ++c) {
        if (tid == 0) {
          T s = sqrt_(Dl[c][c]);
          Dl[c][c] = s;
          Dl[c][NB] = (T)1 / s;
        }
        lfence();
        const T cinv = Dl[c][NB];
        if (tid > c && tid < NB) Dl[tid][c] *= cinv;
        lfence();
        const int w = NB - 1 - c;
        for (int e = tid; e < w * w; e += 64) {
          const int r = c + 1 + e / w;
          const int k = c + 1 + e % w;
          Dl[r][k] -= Dl[r][c] * Dl[k][c];
        }
        lfence();
      }
    }
    __syncthreads();
    // write diag block back (lower)
    for (int e = tid; e < NB * NB; e += 512) {
      const int r = e / NB, c = e - r * NB;
      if (c <= r) A[(size_t)(j0 + r) * NP + (j0 + c)] = Dl[r][c];
    }
    if (Mrem > 0) {
      // panel solve: row i below diag:  v <- v * D^-T
      for (int i = r0 + tid; i < NP; i += 512) {
        T v[NB];
        const T* ar = A + (size_t)i * NP + j0;
        if constexpr (sizeof(T) == 4) {
          const float4* a4 = reinterpret_cast<const float4*>(ar);
#pragma unroll
          for (int q = 0; q < 8; ++q) {
            const float4 t4 = a4[q];
            v[q * 4] = t4.x; v[q * 4 + 1] = t4.y; v[q * 4 + 2] = t4.z; v[q * 4 + 3] = t4.w;
          }
        } else {
#pragma unroll
          for (int c = 0; c < NB; ++c) v[c] = ar[c];
        }
#pragma unroll
        for (int c = 0; c < NB; ++c) {
          T acc = v[c];
          for (int k = 0; k < c; ++k) acc -= v[k] * Dl[c][k];
          v[c] = acc * Dl[c][NB];
        }
        T* aw = A + (size_t)i * NP + j0;
        if constexpr (sizeof(T) == 4) {
          float4* a4w = reinterpret_cast<float4*>(aw);
#pragma unroll
          for (int q = 0; q < 8; ++q)
            a4w[q] = make_float4(v[q * 4], v[q * 4 + 1], v[q * 4 + 2], v[q * 4 + 3]);
        } else {
#pragma unroll
          for (int c = 0; c < NB; ++c) aw[c] = v[c];
        }
        const int ri = i - r0, ti = ri >> 3, rr = ri & 7;
#pragma unroll
        for (int c = 0; c < NB; ++c) PTc[ti][c * 8 + rr] = v[c];
      }
      __syncthreads();
      // trailing update, 8x8 register tiles over lower triangle
      const int nt = Mrem >> 3;
      const int ntile = nt * (nt + 1) / 2;
      for (int tix = tid; tix < ntile; tix += 512) {
        int ti = (int)((sqrtf(8.0f * (float)tix + 1.0f) - 1.0f) * 0.5f);
        while ((ti + 1) * (ti + 2) / 2 <= tix) ++ti;
        while (ti * (ti + 1) / 2 > tix) --ti;
        const int tj = tix - ti * (ti + 1) / 2;
        T acc[8][8];
#pragma unroll
        for (int r = 0; r < 8; ++r)
#pragma unroll
          for (int c = 0; c < 8; ++c) acc[r][c] = (T)0;
        for (int p = 0; p < NB; ++p) {
          T a[8], b[8];
          if constexpr (sizeof(T) == 4) {
            const float4 al = *reinterpret_cast<const float4*>(&PTc[ti][p * 8]);
            const float4 ah = *reinterpret_cast<const float4*>(&PTc[ti][p * 8 + 4]);
            const float4 bl = *reinterpret_cast<const float4*>(&PTc[tj][p * 8]);
            const float4 bh = *reinterpret_cast<const float4*>(&PTc[tj][p * 8 + 4]);
            a[0] = al.x; a[1] = al.y; a[2] = al.z; a[3] = al.w;
            a[4] = ah.x; a[5] = ah.y; a[6] = ah.z; a[7] = ah.w;
            b[0] = bl.x; b[1] = bl.y; b[2] = bl.z; b[3] = bl.w;
            b[4] = bh.x; b[5] = bh.y; b[6] = bh.z; b[7] = bh.w;
          } else {
#pragma unroll
            for (int r = 0; r < 8; ++r) { a[r] = PTc[ti][p * 8 + r]; b[r] = PTc[tj][p * 8 + r]; }
          }
#pragma unroll
          for (int r = 0; r < 8; ++r)
#pragma unroll
            for (int c = 0; c < 8; ++c) acc[r][c] += a[r] * b[c];
        }
        const int gi = r0 + ti * 8, gj = r0 + tj * 8;
        if constexpr (sizeof(T) == 4) {
#pragma unroll
          for (int r = 0; r < 8; ++r) {
            float4* aw = reinterpret_cast<float4*>(A + (size_t)(gi + r) * NP + gj);
            float4 x0 = aw[0], x1 = aw[1];
            x0.x -= acc[r][0]; x0.y -= acc[r][1]; x0.z -= acc[r][2]; x0.w -= acc[r][3];
            x1.x -= acc[r][4]; x1.y -= acc[r][5]; x1.z -= acc[r][6]; x1.w -= acc[r][7];
            aw[0] = x0; aw[1] = x1;
          }
        } else {
#pragma unroll
          for (int r = 0; r < 8; ++r)
#pragma unroll
            for (int c = 0; c < 8; ++c)
              A[(size_t)(gi + r) * NP + (gj + c)] -= acc[r][c];
        }
      }
      __syncthreads();
    }
  }
  // ---- fused diag-block inverses: wave w handles blocks b = w, w+8
  __syncthreads();
  const int wv = tid >> 6, lane = tid & 63;
  for (int b = wv; b < NBLK; b += 8) {
    if (lane < NB) {
      const int c = lane;                 // lane owns column c of D^-1
      const T* D = A + (size_t)(b * NB) * NP + (size_t)(b * NB);
      T v[NB];
#pragma unroll
      for (int r = 0; r < NB; ++r) {
        if (r < c) { v[r] = (T)0; continue; }
        const T dia = D[(size_t)r * NP + r];
        if (r == c) { v[r] = (T)1 / dia; continue; }
        T acc = (T)0;
#pragma unroll
        for (int k = 0; k < NB - 1; ++k) {
          if (k >= c && k < r) acc += D[(size_t)r * NP + k] * v[k];
        }
        v[r] = -acc / dia;
      }
      T* out = Dinv + ((size_t)id * NBLK + b) * NB * NB;
#pragma unroll
      for (int r = 0; r < NB; ++r) out[r * NB + c] = v[r];   // coalesced
    }
  }
}

// -------- W = L^-1, column-block-parallel: one WG per (matrix, column-block J)
template <typename T>
__global__ __launch_bounds__(256) void k_trtri2(
    const T* __restrict__ Lb, T* __restrict__ Wb, const T* __restrict__ Dinv) {
  const int J   = blockIdx.x % NBLK;
  const int mat = blockIdx.x / NBLK;
  const T* L  = Lb + (size_t)mat * NP * NP;
  T* W        = Wb + (size_t)mat * NP * NP;
  const T* Dv = Dinv + (size_t)mat * NBLK * NB * NB;
  __shared__ T Xs[NBLK][NB][NB + 4];
  __shared__ T Ss[NB][NB + 4];
  const int tid = threadIdx.x;
  const int r  = tid >> 3;            // 0..31
  const int c0 = (tid & 7) * 4;       // 0,4,...,28
  // X[J] = Dinv_J ; W[J][J] = X[J]
  {
    const T* Dj = Dv + (size_t)J * NB * NB + (size_t)r * NB + c0;
    const T x0 = Dj[0], x1 = Dj[1], x2 = Dj[2], x3 = Dj[3];
    Xs[J][r][c0] = x0; Xs[J][r][c0 + 1] = x1; Xs[J][r][c0 + 2] = x2; Xs[J][r][c0 + 3] = x3;
    T* wr = W + (size_t)(J * NB + r) * NP + J * NB + c0;
    wr[0] = x0; wr[1] = x1; wr[2] = x2; wr[3] = x3;
  }
  __syncthreads();
  for (int I = J + 1; I < NBLK; ++I) {
    // S = sum_{K=J}^{I-1} L[I][K] * X[K]
    T s0 = (T)0, s1 = (T)0, s2 = (T)0, s3 = (T)0;
    const T* Lrow = L + (size_t)(I * NB + r) * NP;
    for (int K = J; K < I; ++K) {
      const T* Ls = Lrow + K * NB;
      if constexpr (sizeof(T) == 4) {
        const float4* L4 = reinterpret_cast<const float4*>(Ls);
#pragma unroll
        for (int q = 0; q < 8; ++q) {
          const float4 a4 = L4[q];
          const float aa[4] = {a4.x, a4.y, a4.z, a4.w};
#pragma unroll
          for (int u = 0; u < 4; ++u) {
            const T a = aa[u];
            const T* xr = &Xs[K][q * 4 + u][c0];
            s0 += a * xr[0]; s1 += a * xr[1]; s2 += a * xr[2]; s3 += a * xr[3];
          }
        }
      } else {
#pragma unroll
        for (int k = 0; k < NB; ++k) {
          const T a = Ls[k];
          const T* xr = &Xs[K][k][c0];
          s0 += a * xr[0]; s1 += a * xr[1]; s2 += a * xr[2]; s3 += a * xr[3];
        }
      }
    }
    Ss[r][c0] = s0; Ss[r][c0 + 1] = s1; Ss[r][c0 + 2] = s2; Ss[r][c0 + 3] = s3;
    __syncthreads();
    // X[I] = -Dinv_I * S
    const T* Di = Dv + (size_t)I * NB * NB + (size_t)r * NB;
    T x0 = (T)0, x1 = (T)0, x2 = (T)0, x3 = (T)0;
#pragma unroll
    for (int k = 0; k < NB; ++k) {
      const T a = Di[k];
      const T* sr = &Ss[k][c0];
      x0 -= a * sr[0]; x1 -= a * sr[1]; x2 -= a * sr[2]; x3 -= a * sr[3];
    }
    Xs[I][r][c0] = x0; Xs[I][r][c0 + 1] = x1; Xs[I][r][c0 + 2] = x2; Xs[I][r][c0 + 3] = x3;
    T* wr = W + (size_t)(I * NB + r) * NP + J * NB + c0;
    wr[0] = x0; wr[1] = x1; wr[2] = x2; wr[3] = x3;
    __syncthreads();
  }
}

// --------------------------------------------------- S5: invK = WK^T WK (fp64)
__global__ __launch_bounds__(256) void k_invK(
    const double* __restrict__ WK, double* __restrict__ invK64, float* __restrict__ invK32) {
  const int g = blockIdx.x * 256 + threadIdx.x;
  if (g >= NP * NP) return;
  const int j = g % NP, i = g / NP;
  const int k0 = (i > j) ? i : j;
  double acc = 0.0;
  for (int k = k0; k < NP; ++k) acc += WK[(size_t)k * NP + i] * WK[(size_t)k * NP + j];
  invK64[g] = acc;
  invK32[g] = (float)acc;
}

// ------------------------- S6: dh0 = diag(inv(invK32)) ~= diag(Kt - Kt*E*Kt)
__global__ __launch_bounds__(256) void k_EK(
    const float* __restrict__ invK32, const double* __restrict__ invK64,
    const double* __restrict__ Kt, double* __restrict__ M1) {
  const int g = blockIdx.x * 256 + threadIdx.x;
  if (g >= NP * NP) return;
  const int j = g % NP, i = g / NP;
  double acc = 0.0;
  for (int s = 0; s < NP; ++s) {
    const double e = (double)invK32[(size_t)i * NP + s] - invK64[(size_t)i * NP + s];
    acc += e * Kt[(size_t)s * NP + j];
  }
  M1[g] = acc;
}

__global__ __launch_bounds__(320) void k_dh0(
    const double* __restrict__ Kt, const double* __restrict__ M1, float* __restrict__ dh0) {
  const int t = threadIdx.x;
  if (t >= Tt) return;
  double acc = 0.0;
  for (int s = 0; s < NP; ++s) acc += Kt[(size_t)t * NP + s] * M1[(size_t)s * NP + t];
  dh0[t] = (float)(Kt[(size_t)t * NP + t] - acc);
}

__global__ __launch_bounds__(256) void k_init(
    const float* __restrict__ dh0, float* __restrict__ mu, float* __restrict__ dh) {
  const int g = blockIdx.x * 256 + threadIdx.x;
  if (g >= Mb * Tt * NL) return;
  mu[g] = 0.f;
  dh[g] = dh0[(g / NL) % Tt];
}

// ---------------------------------------------------------------- I1: lambda
__global__ __launch_bounds__(256) void k_lambda(
    const float* __restrict__ WA, const float* __restrict__ mu,
    const float* __restrict__ dh, const float* __restrict__ biasp,
    float* __restrict__ lam) {
  const int g = blockIdx.x * 256 + threadIdx.x;
  if (g >= Mb * Tt * Nn) return;
  const int mt = g / Nn;
  const float b = biasp[0];
  const float4* wa = reinterpret_cast<const float4*>(WA + (size_t)g * NL);
  const float4* mp = reinterpret_cast<const float4*>(mu + (size_t)mt * NL);
  const float4* dp = reinterpret_cast<const float4*>(dh + (size_t)mt * NL);
  const float4 w0 = wa[0], w1 = wa[1];
  const float4 m0 = mp[0], m1 = mp[1];
  const float4 h0 = dp[0], h1 = dp[1];
  float e = b;
  e += w0.x * (m0.x + 0.5f * w0.x * h0.x);
  e += w0.y * (m0.y + 0.5f * w0.y * h0.y);
  e += w0.z * (m0.z + 0.5f * w0.z * h0.z);
  e += w0.w * (m0.w + 0.5f * w0.w * h0.w);
  e += w1.x * (m1.x + 0.5f * w1.x * h1.x);
  e += w1.y * (m1.y + 0.5f * w1.y * h1.y);
  e += w1.z * (m1.z + 0.5f * w1.z * h1.z);
  e += w1.w * (m1.w + 0.5f * w1.w * h1.w);
  lam[g] = expf(e);
}

// ---------------------------------------------------------------- I2: grad, d
__global__ __launch_bounds__(320) void k_grad_d(
    const float* __restrict__ WB, const float* __restrict__ Yt,
    const float* __restrict__ lam, const float* __restrict__ invK32,
    const float* __restrict__ mu, float* __restrict__ grad, float* __restrict__ dvec) {
  const int ml = blockIdx.x;
  const int m = ml / NL, l = ml % NL;
  const int t = threadIdx.x;
  __shared__ float mus[NP];
  mus[t] = (t < Tt) ? mu[((size_t)m * Tt + t) * NL + l] : 0.f;
  __syncthreads();
  float g1 = 0.f, dd = 0.f;
  if (t < Tt) {
    const float4* wb = reinterpret_cast<const float4*>(WB + ((size_t)ml * Tt + t) * Nn);
    const float4* yt = reinterpret_cast<const float4*>(Yt + ((size_t)m * Tt + t) * Nn);
    const float4* la = reinterpret_cast<const float4*>(lam + ((size_t)m * Tt + t) * Nn);
    for (int q = 0; q < Nn / 4; ++q) {
      const float4 w = wb[q], y = yt[q], v = la[q];
      g1 += w.x * (y.x - v.x) + w.y * (y.y - v.y) + w.z * (y.z - v.z) + w.w * (y.w - v.w);
      dd += w.x * w.x * v.x + w.y * w.y * v.y + w.z * w.z * v.z + w.w * w.w * v.w;
    }
  }
  float g2 = 0.f;
  for (int s = 0; s < Tt; ++s)                   // invK symmetric: coalesced rows
    g2 += invK32[(size_t)s * NP + t] * mus[s];
  if (t < Tt) {
    grad[(size_t)ml * Tt + t] = g1 - g2;
    dvec[(size_t)ml * Tt + t] = dd;
  }
}

// ------------------------------- I5: dh = -colsum(W^2); mu += 0.5 * A^-1 grad
__global__ __launch_bounds__(320) void k_solve(
    const float* __restrict__ Wb, const float* __restrict__ invK32,
    const float* __restrict__ grad, const float* __restrict__ dvec,
    float* __restrict__ mu, float* __restrict__ dh) {
  const int ml = blockIdx.x;
  const int m = ml / NL, l = ml % NL;
  const float* W = Wb + (size_t)ml * NP * NP;
  const int t = threadIdx.x;                     // 0..319
  __shared__ float  gs[NP];
  __shared__ float  Wblk[NB][NP + 13];
  __shared__ float  part[NB][11];
  __shared__ double partd[NB][11];
  __shared__ float  zv[NB];
  __shared__ double xs[NP];
  __shared__ double rs[NP];
  gs[t] = (t < Tt) ? grad[(size_t)ml * Tt + t] : 0.f;
  __syncthreads();
  float yacc = 0.f, dhacc = 0.f;
  // pass 1: x0 = W^T W g  (+ dh colsums)
  for (int I = 0; I < NBLK; ++I) {
    for (int e = t; e < NB * NP; e += 320)
      Wblk[e / NP][e % NP] = W[(size_t)(I * NB + e / NP) * NP + (e % NP)];
    __syncthreads();
    {
      const int r = t & 31, c = t >> 5;
      float p = 0.f;
      if (c <= I) {
        const int k0 = c * NB;
        for (int k = 0; k < NB; ++k) p += Wblk[r][k0 + k] * gs[k0 + k];
      }
      part[r][c] = p;
    }
    __syncthreads();
    if (t < NB) {
      float z = 0.f;
      for (int c = 0; c <= I; ++c) z += part[t][c];
      zv[t] = z;
    }
    __syncthreads();
    if (t < (I + 1) * NB) {
      float ya = 0.f, dha = 0.f;
      for (int r = 0; r < NB; ++r) {
        const float w = Wblk[r][t];
        ya += w * zv[r];
        dha += w * w;
      }
      yacc += ya; dhacc += dha;
    }
    __syncthreads();
  }
  xs[t] = (double)yacc;
  __syncthreads();
  // pass 2: fp64 residual r = g - (invK + diag(d)) x
  for (int I = 0; I < NBLK; ++I) {
    for (int e = t; e < NB * NP; e += 320)
      Wblk[e / NP][e % NP] = invK32[(size_t)(I * NB + e / NP) * NP + (e % NP)];
    __syncthreads();
    {
      const int r = t & 31, c = t >> 5;
      double p = 0.0;
      const int k0 = c * NB;
      for (int k = 0; k < NB; ++k) p += (double)Wblk[r][k0 + k] * xs[k0 + k];
      partd[r][c] = p;
    }
    __syncthreads();
    if (t < NB) {
      double av = 0.0;
      for (int c = 0; c < NBLK; ++c) av += partd[t][c];
      const int row = I * NB + t;
      const double dterm = (row < Tt) ? (double)dvec[(size_t)ml * Tt + row] * xs[row] : 0.0;
      rs[row] = (double)gs[row] - av - dterm;
    }
    __syncthreads();
  }
  // pass 3: delta = W^T W r ; x += delta
  gs[t] = (float)rs[t];
  __syncthreads();
  float y2 = 0.f;
  for (int I = 0; I < NBLK; ++I) {
    for (int e = t; e < NB * NP; e += 320)
      Wblk[e / NP][e % NP] = W[(size_t)(I * NB + e / NP) * NP + (e % NP)];
    __syncthreads();
    {
      const int r = t & 31, c = t >> 5;
      float p = 0.f;
      if (c <= I) {
        const int k0 = c * NB;
        for (int k = 0; k < NB; ++k) p += Wblk[r][k0 + k] * gs[k0 + k];
      }
      part[r][c] = p;
    }
    __syncthreads();
    if (t < NB) {
      float z = 0.f;
      for (int c = 0; c <= I; ++c) z += part[t][c];
      zv[t] = z;
    }
    __syncthreads();
    if (t < (I + 1) * NB) {
      float ya = 0.f;
      for (int r = 0; r < NB; ++r) ya += Wblk[r][t] * zv[r];
      y2 += ya;
    }
    __syncthreads();
  }
  xs[t] += (double)y2;
  if (t < Tt) {
    const size_t idx = ((size_t)m * Tt + t) * NL + l;
    mu[idx] = mu[idx] + (float)(0.5 * xs[t]);     // LR = 0.5, mu += LR * A^-1 g
    dh[idx] = -dhacc;                             // dh for next iteration
  }
}

// ---------------------------------------------------------------- F1: output
__global__ __launch_bounds__(256) void k_out(
    const float* __restrict__ mu, float* __restrict__ out) {
  const int g = blockIdx.x * 256 + threadIdx.x;   // g = (m*NL + l)*Tt + t
  if (g >= Mb * NL * Tt) return;
  const int t = g % Tt;
  const int ml = g / Tt;
  const int m = ml / NL, l = ml % NL;
  out[g] = mu[((size_t)m * Tt + t) * NL + l];
}

// ------------------------------------------------------------------- launcher
extern "C" void kernel_launch(void* const* d_in, const int* in_sizes, int n_in,
                              void* d_out, int out_size, void* d_ws, size_t ws_size,
                              hipStream_t stream) {
  (void)in_sizes; (void)n_in; (void)out_size;
  const float* Yraw  = (const float*)d_in[0];
  const float* kern  = (const float*)d_in[1];
  const float* wproj = (const float*)d_in[2];
  const float* K     = (const float*)d_in[3];
  const float* biasp = (const float*)d_in[4];
  float* out = (float*)d_out;

  char* base = (char*)d_ws;
  size_t off = 0;
  auto alloc = [&](size_t bytes) -> void* {
    void* p = base + off;
    off += (bytes + 511) & ~(size_t)511;
    return p;
  };
  float*  WA     = (float*) alloc((size_t)Mb * Tt * Nn * NL * 4);
  float*  WB     = (float*) alloc((size_t)Mb * Tt * Nn * NL * 4);
  float*  Yt     = (float*) alloc((size_t)Mb * Tt * Nn * 4);
  float*  lam    = (float*) alloc((size_t)Mb * Tt * Nn * 4);
  float*  mu     = (float*) alloc((size_t)Mb * Tt * NL * 4);
  float*  dh     = (float*) alloc((size_t)Mb * Tt * NL * 4);
  float*  grad   = (float*) alloc((size_t)ML * Tt * 4);
  float*  dvec   = (float*) alloc((size_t)ML * Tt * 4);
  float*  Lbuf   = (float*) alloc((size_t)ML * NP * NP * 4);
  float*  Wbuf   = (float*) alloc((size_t)ML * NP * NP * 4);
  float*  DinvF  = (float*) alloc((size_t)ML * NBLK * NB * NB * 4);
  float*  invK32 = (float*) alloc((size_t)NP * NP * 4);
  double* Kt64   = (double*)alloc((size_t)NP * NP * 8);
  double* Kwork  = (double*)alloc((size_t)NP * NP * 8);
  double* WK64   = (double*)alloc((size_t)NP * NP * 8);
  double* invK64 = (double*)alloc((size_t)NP * NP * 8);
  double* M1     = (double*)alloc((size_t)NP * NP * 8);
  double* Dinv64 = (double*)alloc((size_t)NBLK * NB * NB * 8);
  float*  dh0    = (float*) alloc((size_t)NP * 4);
  if (off > ws_size) return;   // workspace too small -> visible as wrong output

  const int gMTN = (Mb * Tt * Nn) / 256;       // 1800
  const int gNP2 = (NP * NP + 255) / 256;      // 400
  const int gMTL = (Mb * Tt * NL + 255) / 256; // 150

  // setup
  k_weights<<<gMTN, 256, 0, stream>>>(Yraw, kern, wproj, WA, WB, Yt);
  k_buildK<<<gNP2, 256, 0, stream>>>(K, Kt64, Kwork);
  k_chol<double, false><<<1, 512, 0, stream>>>(Kwork, nullptr, nullptr, Dinv64);
  k_trtri2<double><<<NBLK, 256, 0, stream>>>(Kwork, WK64, Dinv64);
  k_invK<<<gNP2, 256, 0, stream>>>(WK64, invK64, invK32);
  k_EK<<<gNP2, 256, 0, stream>>>(invK32, invK64, Kt64, M1);
  k_dh0<<<1, 320, 0, stream>>>(Kt64, M1, dh0);
  k_init<<<gMTL, 256, 0, stream>>>(dh0, mu, dh);

  // 5 VI iterations
  for (int it = 0; it < 5; ++it) {
    k_lambda<<<gMTN, 256, 0, stream>>>(WA, mu, dh, biasp, lam);
    k_grad_d<<<ML, 320, 0, stream>>>(WB, Yt, lam, invK32, mu, grad, dvec);
    k_chol<float, true><<<ML, 512, 0, stream>>>(Lbuf, invK32, dvec, DinvF);
    k_trtri2<float><<<ML * NBLK, 256, 0, stream>>>(Lbuf, Wbuf, DinvF);
    k_solve<<<ML, 320, 0, stream>>>(Wbuf, invK32, grad, dvec, mu, dh);
  }
  k_out<<<gMTL, 256, 0, stream>>>(mu, out);
}

// Round 6
// 2200.270 us; speedup vs baseline: 2.9053x; 1.8188x over previous
//
// FCGPFA variational iteration for MI355X (gfx950). Round 6: low-rank Woodbury
// with the two eps-amplified numerics fixed vs round 5 (which ran but failed
// absmax 3.59): (1) pivoted Cholesky of K now in fp64 (global C64, no fp32
// noise-floor garbage columns); (2) Q kept fp64 and the grad projection
// mu - C Q C^T mu computed in fp64 before the x1000 (Q computed from the SAME
// fp32 C used in the sandwich -> Woodbury identity exact for Khat = C32 C32^T,
// ||Khat - K|| ~ 6e-6 << eps).
//
// Algorithm:
//   Fixed-pivot fp64 Cholesky  K ~= C C^T  (C: 300x96, pivots (103k) mod 300)
//   R = eps*I + C32^T C32 (fp64), Q64 = R^-1  ->  invK = (1/eps)(I - C Q C^T)
// Per iteration per system (m,l), s_t = 1/(1+eps*d_t), delta_t = d_t*s_t:
//   Mhat = I + C^T diag(delta) C   (96x96, cond <~ 4 -> fp32 chol solid)
//   A^-1 = diag(eps*s) + diag(s) C Mhat^-1 C^T diag(s)   [scalar-case verified]
//   dh   = -(eps*s + s^2 ||W c_t||^2),  W = chol(Mhat)^-1
//   grad = g1 - (1/eps)(mu - C q),  q = Q (C^T mu)        [fp64 path]
//   mu  += 0.5 * (eps*s*grad + s * C (W^T W (C^T (s*grad))))
//
#include <hip/hip_runtime.h>
#include <math.h>

namespace {
constexpr int Mb   = 16;    // trials
constexpr int Nn   = 96;    // neurons
constexpr int NTF  = 350;   // full time
constexpr int Tt   = 300;   // sliced time
constexpr int NSUB = 8;
constexpr int NTAU = 20;
constexpr int NL   = 8;     // latents
constexpr int ML   = Mb * NL;   // 128 systems
constexpr int R_   = 96;    // low-rank dimension (3 x 32)
constexpr int TP   = 320;   // padded time (10 x 32)
constexpr float EPS  = 0.001f;
}

__device__ __forceinline__ float  sqrt_(float x)  { return sqrtf(x); }
__device__ __forceinline__ double sqrt_(double x) { return sqrt(x); }

// wave-local LDS fence (single-wave synchronous sections) -- proven r1/r2
__device__ __forceinline__ void lfence() {
  asm volatile("s_waitcnt lgkmcnt(0)" ::: "memory");
}

// ---------------- 32x32 GEMM helpers on 256 threads --------------------------
template <typename T, bool ACC>
__device__ __forceinline__ void gemm32(T* __restrict__ D, const T* __restrict__ A,
                                       const T* __restrict__ B, int lda, int ldb,
                                       int ldd, int tid) {
  // D[r][c] (+)= sum_k A[r][k] * B[k][c]
  const int r = tid & 31, c0 = (tid >> 5) * 4;
  T a0 = ACC ? D[r * ldd + c0 + 0] : (T)0;
  T a1 = ACC ? D[r * ldd + c0 + 1] : (T)0;
  T a2 = ACC ? D[r * ldd + c0 + 2] : (T)0;
  T a3 = ACC ? D[r * ldd + c0 + 3] : (T)0;
  for (int k = 0; k < 32; ++k) {
    const T a = A[r * lda + k];
    a0 += a * B[k * ldb + c0 + 0];
    a1 += a * B[k * ldb + c0 + 1];
    a2 += a * B[k * ldb + c0 + 2];
    a3 += a * B[k * ldb + c0 + 3];
  }
  D[r * ldd + c0 + 0] = a0; D[r * ldd + c0 + 1] = a1;
  D[r * ldd + c0 + 2] = a2; D[r * ldd + c0 + 3] = a3;
}

template <typename T>
__device__ __forceinline__ void gemm32_neg(T* __restrict__ D, const T* __restrict__ A,
                                           const T* __restrict__ B, int lda, int ldb,
                                           int ldd, int tid) {
  const int r = tid & 31, c0 = (tid >> 5) * 4;
  T a0 = (T)0, a1 = (T)0, a2 = (T)0, a3 = (T)0;
  for (int k = 0; k < 32; ++k) {
    const T a = A[r * lda + k];
    a0 += a * B[k * ldb + c0 + 0];
    a1 += a * B[k * ldb + c0 + 1];
    a2 += a * B[k * ldb + c0 + 2];
    a3 += a * B[k * ldb + c0 + 3];
  }
  D[r * ldd + c0 + 0] = -a0; D[r * ldd + c0 + 1] = -a1;
  D[r * ldd + c0 + 2] = -a2; D[r * ldd + c0 + 3] = -a3;
}

// ------------- 96x96 Cholesky (lower) + W = L^-1, 256 threads ---------------
// A (stride 97) LDS: input full symmetric; on exit lower = L.
// W (stride 97, LDS or global): block-lower inverse. Tb: 32x33 scratch.
// rd: 96 inv-pivots. V3: 3*32*33 scratch. Round-1/2 proven patterns only.
template <typename T>
__device__ void chol96_trtri96(T* __restrict__ A, T* __restrict__ W,
                               T* __restrict__ Tb, T* __restrict__ rd,
                               T* __restrict__ V3, int tid) {
  const int LD = 97;
  for (int pb = 0; pb < 3; ++pb) {
    const int o = pb * 32;
    // stage diag block (lower) into Tb as Dl[32][33]; col 32 = inv pivot
    for (int e = tid; e < 32 * 32; e += 256) {
      const int r = e >> 5, c = e & 31;
      Tb[r * 33 + c] = (c <= r) ? A[(o + r) * LD + (o + c)] : (T)0;
    }
    __syncthreads();
    // wave-synchronous 32x32 mini-Cholesky (wave 0) -- proven r1/r2 pattern
    if (tid < 64) {
      for (int c = 0; c < 32; ++c) {
        if (tid == 0) {
          const T s = sqrt_(Tb[c * 33 + c]);
          Tb[c * 33 + c] = s;
          Tb[c * 33 + 32] = (T)1 / s;
        }
        lfence();
        const T cinv = Tb[c * 33 + 32];
        if (tid > c && tid < 32) Tb[tid * 33 + c] *= cinv;
        lfence();
        const int w = 31 - c;
        for (int e = tid; e < w * w; e += 64) {
          const int r = c + 1 + e / w;
          const int k = c + 1 + e % w;
          Tb[r * 33 + k] -= Tb[r * 33 + c] * Tb[k * 33 + c];
        }
        lfence();
      }
    }
    __syncthreads();
    // write back diag block + inv pivots
    for (int e = tid; e < 32 * 32; e += 256) {
      const int r = e >> 5, c = e & 31;
      if (c <= r) A[(o + r) * LD + (o + c)] = Tb[r * 33 + c];
    }
    if (tid < 32) rd[o + tid] = Tb[tid * 33 + 32];
    __syncthreads();
    const int rows = 64 - o;
    if (rows > 0) {
      // panel solve: one thread per row below the diag block (proven r2 form)
      if (tid < rows) {
        const int i = o + 32 + tid;
        T v[32];
#pragma unroll
        for (int c = 0; c < 32; ++c) v[c] = A[i * LD + o + c];
#pragma unroll
        for (int c = 0; c < 32; ++c) {
          T acc = v[c];
          for (int k = 0; k < c; ++k) acc -= v[k] * Tb[c * 33 + k];
          v[c] = acc * Tb[c * 33 + 32];
        }
#pragma unroll
        for (int c = 0; c < 32; ++c) A[i * LD + o + c] = v[c];
      }
      __syncthreads();
      // trailing update, 4x4 register tiles over lower triangle
      const int nt = rows / 4;
      const int ntile = nt * (nt + 1) / 2;
      for (int tix = tid; tix < ntile; tix += 256) {
        int ti = (int)((sqrtf(8.f * (float)tix + 1.f) - 1.f) * 0.5f);
        while ((ti + 1) * (ti + 2) / 2 <= tix) ++ti;
        while (ti * (ti + 1) / 2 > tix) --ti;
        const int tj = tix - ti * (ti + 1) / 2;
        const int gi = o + 32 + ti * 4, gj = o + 32 + tj * 4;
        T acc[4][4];
#pragma unroll
        for (int r = 0; r < 4; ++r)
#pragma unroll
          for (int c = 0; c < 4; ++c) acc[r][c] = (T)0;
        for (int k = 0; k < 32; ++k) {
          T a[4], b[4];
#pragma unroll
          for (int r = 0; r < 4; ++r) a[r] = A[(gi + r) * LD + o + k];
#pragma unroll
          for (int c = 0; c < 4; ++c) b[c] = A[(gj + c) * LD + o + k];
#pragma unroll
          for (int r = 0; r < 4; ++r)
#pragma unroll
            for (int c = 0; c < 4; ++c) acc[r][c] += a[r] * b[c];
        }
#pragma unroll
        for (int r = 0; r < 4; ++r)
#pragma unroll
          for (int c = 0; c < 4; ++c)
            A[(gi + r) * LD + (gj + c)] -= acc[r][c];
      }
      __syncthreads();
    }
  }
  // diag-block inverses: 3 waves concurrent, lane = column (lane-private LDS col)
  {
    const int wv = tid >> 6, lane = tid & 63;
    if (wv < 3 && lane < 32) {
      const int o = wv * 32, c = lane;
      T* V = V3 + wv * 32 * 33;
      V[c * 33 + c] = rd[o + c];
      for (int r = c + 1; r < 32; ++r) {
        T acc = (T)0;
        for (int k = c; k < r; ++k)
          acc += A[(o + r) * LD + (o + k)] * V[k * 33 + c];
        V[r * 33 + c] = -acc * rd[o + r];
      }
      for (int r = 0; r < 32; ++r)
        W[(o + r) * LD + (o + c)] = (r < c) ? (T)0 : V[r * 33 + c];
    }
  }
  __syncthreads();
  // off-diagonal blocks of W = L^-1
  T* L10 = A + 32 * LD + 0;
  T* L20 = A + 64 * LD + 0;
  T* L21 = A + 64 * LD + 32;
  T* W00 = W + 0;
  T* W10 = W + 32 * LD + 0;
  T* W11 = W + 32 * LD + 32;
  T* W20 = W + 64 * LD + 0;
  T* W21 = W + 64 * LD + 32;
  T* W22 = W + 64 * LD + 64;
  gemm32<T, false>(Tb, L10, W00, LD, LD, 33, tid); __syncthreads();
  gemm32_neg<T>(W10, W11, Tb, LD, 33, LD, tid);    __syncthreads();
  gemm32<T, false>(Tb, L20, W00, LD, LD, 33, tid); __syncthreads();
  gemm32<T, true>(Tb, L21, W10, LD, LD, 33, tid);  __syncthreads();
  gemm32_neg<T>(W20, W22, Tb, LD, 33, LD, tid);    __syncthreads();
  gemm32<T, false>(Tb, L21, W11, LD, LD, 33, tid); __syncthreads();
  gemm32_neg<T>(W21, W22, Tb, LD, 33, LD, tid);    __syncthreads();
}

// ---------------------------------------------------------------- S1: weights
__global__ __launch_bounds__(256) void k_weights(
    const float* __restrict__ Yraw, const float* __restrict__ kern,
    const float* __restrict__ wproj, float* __restrict__ WA,
    float* __restrict__ WB, float* __restrict__ Yt) {
  __shared__ float sk[NTAU * NSUB];
  __shared__ float sp[NSUB * NL];
  const int tid = threadIdx.x;
  if (tid < NTAU * NSUB) sk[tid] = kern[tid];
  if (tid < NSUB * NL)   sp[tid] = wproj[tid];
  __syncthreads();
  const int g = blockIdx.x * 256 + tid;            // g = (m*Tt + t)*Nn + n
  if (g >= Mb * Tt * Nn) return;
  const int n  = g % Nn;
  const int mt = g / Nn;
  const int t  = mt % Tt;
  const int m  = mt / Tt;
  const float* yr = Yraw + ((size_t)m * Nn + n) * NTF + 30 + t;
  float ya[NTAU + 1];
#pragma unroll
  for (int j = 0; j <= NTAU; ++j) ya[j] = yr[j];
  float gs[NSUB];
#pragma unroll
  for (int s = 0; s < NSUB; ++s) {
    float acc = 0.f;
#pragma unroll
    for (int j = 0; j < NTAU; ++j) acc += ya[j] * sk[(NTAU - 1 - j) * NSUB + s];
    gs[s] = (fabsf(acc) < 1e-5f) ? 0.f : acc;      // reference threshold
  }
  float w[NL];
#pragma unroll
  for (int l = 0; l < NL; ++l) {
    float acc = 0.f;
#pragma unroll
    for (int s = 0; s < NSUB; ++s) acc += gs[s] * sp[s * NL + l];
    w[l] = acc;
  }
  float4* wa4 = reinterpret_cast<float4*>(WA + (size_t)g * NL);
  wa4[0] = make_float4(w[0], w[1], w[2], w[3]);
  wa4[1] = make_float4(w[4], w[5], w[6], w[7]);
#pragma unroll
  for (int l = 0; l < NL; ++l)
    WB[(((size_t)m * NL + l) * Tt + t) * Nn + n] = w[l];
  Yt[g] = ya[NTAU];                                // Yraw[m][n][50+t]
}

// ---- S2: fixed-pivot fp64 Cholesky of K -> C64 (col-major), C32, dh0 -------
__global__ __launch_bounds__(320) void k_pchol(
    const float* __restrict__ K, double* __restrict__ Ccm,  // [R_][TP] col-major
    float* __restrict__ Cg, float* __restrict__ dh0) {
  __shared__ double Cp[R_];
  __shared__ double rho_s;
  const int t = threadIdx.x;             // 0..319
  for (int k = 0; k < R_; ++k) {
    const int p = (k * 103) % Tt;        // fixed well-spread pivot order
    if (t < k) Cp[t] = Ccm[(size_t)t * TP + p];
    __syncthreads();
    double acc = 0.0;
    if (t < Tt) {
      for (int j = 0; j < k; ++j)
        acc += Ccm[(size_t)j * TP + t] * Cp[j];
    }
    if (t == p) rho_s = (double)K[(size_t)p * Tt + p] - acc;
    __syncthreads();
    const double rho = rho_s;
    double cv = 0.0;
    if (rho > 1e-12 && t < Tt)           // guard 3 decades above fp64 noise
      cv = ((double)K[(size_t)p * Tt + t] - acc) / sqrt(rho);
    Ccm[(size_t)k * TP + t] = (t < Tt) ? cv : 0.0;
    __syncthreads();
  }
  // C32 row-major [TP][R_] for the fp32 sandwich path
  for (int e = t; e < TP * R_; e += 320) {
    const int r = e / R_, c = e - r * R_;
    Cg[e] = (float)Ccm[(size_t)c * TP + r];
  }
  // dh0 = diag(C C^T) + eps
  if (t < TP) {
    double s = (t < Tt) ? (double)EPS : 0.0;
    if (t < Tt) {
      for (int j = 0; j < R_; ++j) {
        const double v = Ccm[(size_t)j * TP + t];
        s += v * v;
      }
    }
    dh0[t] = (float)s;
  }
}

// ---------------- S2b: R64 = eps*I + C32^T C32 (fp64, 36 WGs) ---------------
// NOTE: must use C32 (not C64) so the Woodbury identity is exact for C32.
__global__ __launch_bounds__(256) void k_rmul(
    const float* __restrict__ Cg, double* __restrict__ R64) {
  const int e = blockIdx.x * 256 + threadIdx.x;
  if (e >= R_ * R_) return;
  const int i = e / R_, j = e - i * R_;
  double acc = (i == j) ? 0.001 : 0.0;
  for (int r = 0; r < Tt; ++r)
    acc += (double)Cg[(size_t)r * R_ + i] * (double)Cg[(size_t)r * R_ + j];
  R64[e] = acc;
}

// --------------- S3a: chol96+trtri96 of R (fp64), W -> global ---------------
__global__ __launch_bounds__(256) void k_qchol(
    const double* __restrict__ R64, double* __restrict__ W64) {
  __shared__ double A[R_ * (R_ + 1)];    // 74.5 KB
  __shared__ double Tb[32 * 33];
  __shared__ double rd[R_];
  __shared__ double V3[3 * 32 * 33];
  const int tid = threadIdx.x;
  for (int e = tid; e < R_ * R_; e += 256) {
    const int i = e / R_, j = e - i * R_;
    A[i * 97 + j] = R64[e];
  }
  __syncthreads();
  chol96_trtri96<double>(A, W64, Tb, rd, V3, tid);
}

// --------------- S3b: Q64 = W^T W (fp64 throughout) -------------------------
__global__ __launch_bounds__(256) void k_qmul(
    const double* __restrict__ W64, double* __restrict__ Qg) {
  const int e = blockIdx.x * 256 + threadIdx.x;
  if (e >= R_ * R_) return;
  const int i = e / R_, j = e - i * R_;
  const int k0 = (i > j) ? i : j;
  double acc = 0.0;
  for (int k = k0; k < R_; ++k) acc += W64[k * 97 + i] * W64[k * 97 + j];
  Qg[e] = acc;
}

// ---------------------------------------------------------------- S4: init
__global__ __launch_bounds__(256) void k_init(
    const float* __restrict__ dh0, float* __restrict__ mu, float* __restrict__ dh) {
  const int g = blockIdx.x * 256 + threadIdx.x;
  if (g >= Mb * Tt * NL) return;
  mu[g] = 0.f;
  dh[g] = dh0[(g / NL) % Tt];
}

// ---------------------------------------------------------------- I1: lambda
__global__ __launch_bounds__(256) void k_lambda(
    const float* __restrict__ WA, const float* __restrict__ mu,
    const float* __restrict__ dh, const float* __restrict__ biasp,
    float* __restrict__ lam) {
  const int g = blockIdx.x * 256 + threadIdx.x;
  if (g >= Mb * Tt * Nn) return;
  const int mt = g / Nn;
  const float b = biasp[0];
  const float4* wa = reinterpret_cast<const float4*>(WA + (size_t)g * NL);
  const float4* mp = reinterpret_cast<const float4*>(mu + (size_t)mt * NL);
  const float4* dp = reinterpret_cast<const float4*>(dh + (size_t)mt * NL);
  const float4 w0 = wa[0], w1 = wa[1];
  const float4 m0 = mp[0], m1 = mp[1];
  const float4 h0 = dp[0], h1 = dp[1];
  float e = b;
  e += w0.x * (m0.x + 0.5f * w0.x * h0.x);
  e += w0.y * (m0.y + 0.5f * w0.y * h0.y);
  e += w0.z * (m0.z + 0.5f * w0.z * h0.z);
  e += w0.w * (m0.w + 0.5f * w0.w * h0.w);
  e += w1.x * (m1.x + 0.5f * w1.x * h1.x);
  e += w1.y * (m1.y + 0.5f * w1.y * h1.y);
  e += w1.z * (m1.z + 0.5f * w1.z * h1.z);
  e += w1.w * (m1.w + 0.5f * w1.w * h1.w);
  lam[g] = expf(e);
}

// --------------------------------------- I2: g1 = W^T(Y-lam), d = (W^2)^T lam
__global__ __launch_bounds__(320) void k_gd(
    const float* __restrict__ WB, const float* __restrict__ Yt,
    const float* __restrict__ lam, float* __restrict__ g1, float* __restrict__ dvec) {
  const int ml = blockIdx.x;
  const int m = ml / NL;
  const int t = threadIdx.x;
  float ga = 0.f, dd = 0.f;
  if (t < Tt) {
    const float4* wb = reinterpret_cast<const float4*>(WB + ((size_t)ml * Tt + t) * Nn);
    const float4* yt = reinterpret_cast<const float4*>(Yt + ((size_t)m * Tt + t) * Nn);
    const float4* la = reinterpret_cast<const float4*>(lam + ((size_t)m * Tt + t) * Nn);
    for (int q = 0; q < Nn / 4; ++q) {
      const float4 w = wb[q], y = yt[q], v = la[q];
      ga += w.x * (y.x - v.x) + w.y * (y.y - v.y) + w.z * (y.z - v.z) + w.w * (y.w - v.w);
      dd += w.x * w.x * v.x + w.y * w.y * v.y + w.z * w.z * v.z + w.w * w.w * v.w;
    }
  }
  g1[(size_t)ml * TP + t]   = (t < Tt) ? ga : 0.f;
  dvec[(size_t)ml * TP + t] = (t < Tt) ? dd : 0.f;
}

// ------------------- I3: fused Woodbury solve + diag (one WG per system) -----
__global__ __launch_bounds__(256) void k_wood(
    const float* __restrict__ Cg, const double* __restrict__ Qg,
    const float* __restrict__ g1g, const float* __restrict__ dvg,
    float* __restrict__ mug, float* __restrict__ dhg) {
  const int ml = blockIdx.x;
  const int mt = ml / NL, lat = ml % NL;
  const int tid = threadIdx.x;
  __shared__ float Cb[32 * 97];        // C row-block
  __shared__ float Mh[R_ * 97];        // Mhat, then L
  __shared__ float Wm[R_ * 97];        // W = L^-1
  __shared__ float Tb[32 * 33];
  __shared__ float rd[R_];
  __shared__ float V3[3 * 32 * 33];
  __shared__ float muv[TP], gv[TP], sv[TP], dv[TP];   // dv: delta, then s*grad
  __shared__ double pvd[R_], qvd[R_];                 // fp64 grad-projection path
  __shared__ float uv[R_], t1v[R_], yv[R_];
  __shared__ float red[256];
  __shared__ float red2[32];

  // Phase A: load vectors, compute s, delta
  for (int t = tid; t < TP; t += 256) {
    float m_ = 0.f, g_ = 0.f, d_ = 0.f;
    if (t < Tt) {
      m_ = mug[((size_t)mt * Tt + t) * NL + lat];
      g_ = g1g[(size_t)ml * TP + t];
      d_ = dvg[(size_t)ml * TP + t];
    }
    muv[t] = m_; gv[t] = g_;
    const float den = 1.f / (1.f + EPS * d_);
    sv[t] = den;
    dv[t] = d_ * den;
  }
  __syncthreads();

  // Phase B: p = C^T mu (fp64 accum)  and  Mhat = I + C^T diag(delta) C
  float accM[6][6];
#pragma unroll
  for (int i = 0; i < 6; ++i)
#pragma unroll
    for (int j = 0; j < 6; ++j) accM[i][j] = 0.f;
  double run_p = 0.0;
  const int a6 = (tid & 15) * 6;
  const int b6 = (tid >> 4) * 6;
  for (int b = 0; b < 10; ++b) {
    for (int e = tid; e < 32 * R_; e += 256) {
      const int rr = e / R_, cc = e - rr * R_;
      Cb[rr * 97 + cc] = Cg[(size_t)(b * 32 + rr) * R_ + cc];
    }
    __syncthreads();
    if (tid < R_) {
      for (int rr = 0; rr < 32; ++rr)
        run_p += (double)Cb[rr * 97 + tid] * (double)muv[b * 32 + rr];
    }
    for (int rr = 0; rr < 32; ++rr) {
      const float dr = dv[b * 32 + rr];
      float va[6], vb[6];
#pragma unroll
      for (int j = 0; j < 6; ++j) {
        va[j] = Cb[rr * 97 + a6 + j] * dr;
        vb[j] = Cb[rr * 97 + b6 + j];
      }
#pragma unroll
      for (int i = 0; i < 6; ++i)
#pragma unroll
        for (int j = 0; j < 6; ++j) accM[i][j] += va[i] * vb[j];
    }
    __syncthreads();
  }
#pragma unroll
  for (int i = 0; i < 6; ++i)
#pragma unroll
    for (int j = 0; j < 6; ++j) {
      const int gi = a6 + i, gj = b6 + j;
      Mh[gi * 97 + gj] = accM[i][j] + ((gi == gj) ? 1.f : 0.f);
    }
  if (tid < R_) pvd[tid] = run_p;
  __syncthreads();

  // Phase C: q = Q64 p (fp64, Q symmetric, coalesced)
  if (tid < R_) {
    double acc = 0.0;
    for (int j = 0; j < R_; ++j) acc += Qg[(size_t)j * R_ + tid] * pvd[j];
    qvd[tid] = acc;
  }
  __syncthreads();

  // Phase D: grad = g1 - (1/eps)(mu - C q)  [fp64 inner];  u = C^T (s*grad)
  float run_u = 0.f;
  for (int b = 0; b < 10; ++b) {
    for (int e = tid; e < 32 * R_; e += 256) {
      const int rr = e / R_, cc = e - rr * R_;
      Cb[rr * 97 + cc] = Cg[(size_t)(b * 32 + rr) * R_ + cc];
    }
    __syncthreads();
    if (tid < 32) {
      const int t = b * 32 + tid;
      double cq = 0.0;
      for (int k = 0; k < R_; ++k) cq += (double)Cb[tid * 97 + k] * qvd[k];
      const double gnew = (double)gv[t] - 1000.0 * ((double)muv[t] - cq);
      gv[t] = (float)gnew;
      dv[t] = sv[t] * (float)gnew;   // reuse dv as s*grad
    }
    __syncthreads();
    if (tid < R_) {
      for (int rr = 0; rr < 32; ++rr)
        run_u += Cb[rr * 97 + tid] * dv[b * 32 + rr];
    }
    __syncthreads();
  }
  if (tid < R_) uv[tid] = run_u;
  __syncthreads();

  // Phase E: chol(Mhat) + W = L^-1 (in LDS)
  chol96_trtri96<float>(Mh, Wm, Tb, rd, V3, tid);

  // Phase F: y = W^T (W u)
  if (tid < R_) {
    float acc = 0.f;
    for (int j = 0; j <= tid; ++j) acc += Wm[tid * 97 + j] * uv[j];
    t1v[tid] = acc;
  }
  __syncthreads();
  if (tid < R_) {
    float acc = 0.f;
    for (int j = tid; j < R_; ++j) acc += Wm[j * 97 + tid] * t1v[j];
    yv[tid] = acc;
  }
  __syncthreads();

  // Phase G: dh_t = -(eps*s + s^2 ||W c_t||^2);  x = eps*s*grad + s*(C y)
  const int r = tid & 31, ic = tid >> 5;
  for (int b = 0; b < 10; ++b) {
    for (int e = tid; e < 32 * R_; e += 256) {
      const int rr = e / R_, cc = e - rr * R_;
      Cb[rr * 97 + cc] = Cg[(size_t)(b * 32 + rr) * R_ + cc];
    }
    __syncthreads();
    float jsq = 0.f;
    {
      const int i1 = ic * 6, i2 = (15 - ic) * 6;
#pragma unroll
      for (int ii = 0; ii < 6; ++ii) {
        int i = i1 + ii;
        float dot = 0.f;
        for (int k = 0; k <= i; ++k) dot += Wm[i * 97 + k] * Cb[r * 97 + k];
        jsq += dot * dot;
        i = i2 + ii;
        dot = 0.f;
        for (int k = 0; k <= i; ++k) dot += Wm[i * 97 + k] * Cb[r * 97 + k];
        jsq += dot * dot;
      }
    }
    red[tid] = jsq;
    if (ic == 0) {
      float cy = 0.f;
      for (int k = 0; k < R_; ++k) cy += Cb[r * 97 + k] * yv[k];
      red2[r] = cy;
    }
    __syncthreads();
    if (tid < 32) {
      const int t = b * 32 + tid;
      if (t < Tt) {
        float S = 0.f;
#pragma unroll
        for (int q = 0; q < 8; ++q) S += red[q * 32 + tid];
        const float s = sv[t];
        const float x = EPS * s * gv[t] + s * red2[tid];
        const size_t idx = ((size_t)mt * Tt + t) * NL + lat;
        mug[idx] = muv[t] + 0.5f * x;                 // LR = 0.5
        dhg[idx] = -(EPS * s + s * s * S);
      }
    }
    __syncthreads();
  }
}

// ---------------------------------------------------------------- F1: output
__global__ __launch_bounds__(256) void k_out(
    const float* __restrict__ mu, float* __restrict__ out) {
  const int g = blockIdx.x * 256 + threadIdx.x;   // g = (m*NL + l)*Tt + t
  if (g >= Mb * NL * Tt) return;
  const int t = g % Tt;
  const int ml = g / Tt;
  const int m = ml / NL, l = ml % NL;
  out[g] = mu[((size_t)m * Tt + t) * NL + l];
}

// ------------------------------------------------------------------- launcher
extern "C" void kernel_launch(void* const* d_in, const int* in_sizes, int n_in,
                              void* d_out, int out_size, void* d_ws, size_t ws_size,
                              hipStream_t stream) {
  (void)in_sizes; (void)n_in; (void)out_size;
  const float* Yraw  = (const float*)d_in[0];
  const float* kern  = (const float*)d_in[1];
  const float* wproj = (const float*)d_in[2];
  const float* K     = (const float*)d_in[3];
  const float* biasp = (const float*)d_in[4];
  float* out = (float*)d_out;

  char* base = (char*)d_ws;
  size_t off = 0;
  auto alloc = [&](size_t bytes) -> void* {
    void* p = base + off;
    off += (bytes + 511) & ~(size_t)511;
    return p;
  };
  float*  WA   = (float*) alloc((size_t)Mb * Tt * Nn * NL * 4);
  float*  WB   = (float*) alloc((size_t)Mb * Tt * Nn * NL * 4);
  float*  Yt   = (float*) alloc((size_t)Mb * Tt * Nn * 4);
  float*  lam  = (float*) alloc((size_t)Mb * Tt * Nn * 4);
  float*  mu   = (float*) alloc((size_t)Mb * Tt * NL * 4);
  float*  dh   = (float*) alloc((size_t)Mb * Tt * NL * 4);
  float*  g1   = (float*) alloc((size_t)ML * TP * 4);
  float*  dvec = (float*) alloc((size_t)ML * TP * 4);
  float*  Cg   = (float*) alloc((size_t)TP * R_ * 4);
  double* Ccm  = (double*)alloc((size_t)R_ * TP * 8);
  double* Q64  = (double*)alloc((size_t)R_ * R_ * 8);
  double* R64  = (double*)alloc((size_t)R_ * R_ * 8);
  double* W64  = (double*)alloc((size_t)R_ * (R_ + 1) * 8);
  float*  dh0  = (float*) alloc((size_t)TP * 4);
  if (off > ws_size) return;

  const int gMTN = (Mb * Tt * Nn) / 256;       // 1800
  const int gMTL = (Mb * Tt * NL + 255) / 256; // 150
  const int gRR  = (R_ * R_ + 255) / 256;      // 36

  k_weights<<<gMTN, 256, 0, stream>>>(Yraw, kern, wproj, WA, WB, Yt);
  k_pchol<<<1, 320, 0, stream>>>(K, Ccm, Cg, dh0);
  k_rmul<<<gRR, 256, 0, stream>>>(Cg, R64);
  k_qchol<<<1, 256, 0, stream>>>(R64, W64);
  k_qmul<<<gRR, 256, 0, stream>>>(W64, Q64);
  k_init<<<gMTL, 256, 0, stream>>>(dh0, mu, dh);

  for (int it = 0; it < 5; ++it) {
    k_lambda<<<gMTN, 256, 0, stream>>>(WA, mu, dh, biasp, lam);
    k_gd<<<ML, 320, 0, stream>>>(WB, Yt, lam, g1, dvec);
    k_wood<<<ML, 256, 0, stream>>>(Cg, Q64, g1, dvec, mu, dh);
  }
  k_out<<<gMTL, 256, 0, stream>>>(mu, out);
}

// Round 7
// 1621.157 us; speedup vs baseline: 3.9431x; 1.3572x over previous
//
// FCGPFA variational iteration for MI355X (gfx950). Round 7: round-6 Woodbury
// numerics, k_wood split into GEMM-shaped kernels with register tiling and
// vectorized (float2) LDS reads. Per iteration:
//   k_lambda -> k_gd -> k_pre (p,q,grad,u fp64 path) -> k_mhat (256 WGs,
//   Mhat = C^T diag(delta) C, symmetric-half) -> k_cholM (chol96+trtri96 + y)
//   -> k_fin (512 WGs: X = C W^T GEMM -> jsq -> dh, mu update)
//
#include <hip/hip_runtime.h>
#include <math.h>

namespace {
constexpr int Mb   = 16;
constexpr int Nn   = 96;
constexpr int NTF  = 350;
constexpr int Tt   = 300;
constexpr int NSUB = 8;
constexpr int NTAU = 20;
constexpr int NL   = 8;
constexpr int ML   = Mb * NL;   // 128 systems
constexpr int R_   = 96;
constexpr int TP   = 320;
constexpr int CROWS= 384;       // C rows padded for 4 x 96 t-blocks
constexpr float EPS = 0.001f;
}

__device__ __forceinline__ float  sqrt_(float x)  { return sqrtf(x); }
__device__ __forceinline__ double sqrt_(double x) { return sqrt(x); }

__device__ __forceinline__ void lfence() {
  asm volatile("s_waitcnt lgkmcnt(0)" ::: "memory");
}

// ---------------- 32x32 GEMM helpers on 256 threads (proven r5/r6) ----------
template <typename T, bool ACC>
__device__ __forceinline__ void gemm32(T* __restrict__ D, const T* __restrict__ A,
                                       const T* __restrict__ B, int lda, int ldb,
                                       int ldd, int tid) {
  const int r = tid & 31, c0 = (tid >> 5) * 4;
  T a0 = ACC ? D[r * ldd + c0 + 0] : (T)0;
  T a1 = ACC ? D[r * ldd + c0 + 1] : (T)0;
  T a2 = ACC ? D[r * ldd + c0 + 2] : (T)0;
  T a3 = ACC ? D[r * ldd + c0 + 3] : (T)0;
  for (int k = 0; k < 32; ++k) {
    const T a = A[r * lda + k];
    a0 += a * B[k * ldb + c0 + 0];
    a1 += a * B[k * ldb + c0 + 1];
    a2 += a * B[k * ldb + c0 + 2];
    a3 += a * B[k * ldb + c0 + 3];
  }
  D[r * ldd + c0 + 0] = a0; D[r * ldd + c0 + 1] = a1;
  D[r * ldd + c0 + 2] = a2; D[r * ldd + c0 + 3] = a3;
}

template <typename T>
__device__ __forceinline__ void gemm32_neg(T* __restrict__ D, const T* __restrict__ A,
                                           const T* __restrict__ B, int lda, int ldb,
                                           int ldd, int tid) {
  const int r = tid & 31, c0 = (tid >> 5) * 4;
  T a0 = (T)0, a1 = (T)0, a2 = (T)0, a3 = (T)0;
  for (int k = 0; k < 32; ++k) {
    const T a = A[r * lda + k];
    a0 += a * B[k * ldb + c0 + 0];
    a1 += a * B[k * ldb + c0 + 1];
    a2 += a * B[k * ldb + c0 + 2];
    a3 += a * B[k * ldb + c0 + 3];
  }
  D[r * ldd + c0 + 0] = -a0; D[r * ldd + c0 + 1] = -a1;
  D[r * ldd + c0 + 2] = -a2; D[r * ldd + c0 + 3] = -a3;
}

// ------------- 96x96 Cholesky (lower) + W = L^-1 (proven r5/r6) -------------
template <typename T>
__device__ void chol96_trtri96(T* __restrict__ A, T* __restrict__ W,
                               T* __restrict__ Tb, T* __restrict__ rd,
                               T* __restrict__ V3, int tid) {
  const int LD = 97;
  for (int pb = 0; pb < 3; ++pb) {
    const int o = pb * 32;
    for (int e = tid; e < 32 * 32; e += 256) {
      const int r = e >> 5, c = e & 31;
      Tb[r * 33 + c] = (c <= r) ? A[(o + r) * LD + (o + c)] : (T)0;
    }
    __syncthreads();
    if (tid < 64) {
      for (int c = 0; c < 32; ++c) {
        if (tid == 0) {
          const T s = sqrt_(Tb[c * 33 + c]);
          Tb[c * 33 + c] = s;
          Tb[c * 33 + 32] = (T)1 / s;
        }
        lfence();
        const T cinv = Tb[c * 33 + 32];
        if (tid > c && tid < 32) Tb[tid * 33 + c] *= cinv;
        lfence();
        const int w = 31 - c;
        for (int e = tid; e < w * w; e += 64) {
          const int r = c + 1 + e / w;
          const int k = c + 1 + e % w;
          Tb[r * 33 + k] -= Tb[r * 33 + c] * Tb[k * 33 + c];
        }
        lfence();
      }
    }
    __syncthreads();
    for (int e = tid; e < 32 * 32; e += 256) {
      const int r = e >> 5, c = e & 31;
      if (c <= r) A[(o + r) * LD + (o + c)] = Tb[r * 33 + c];
    }
    if (tid < 32) rd[o + tid] = Tb[tid * 33 + 32];
    __syncthreads();
    const int rows = 64 - o;
    if (rows > 0) {
      if (tid < rows) {
        const int i = o + 32 + tid;
        T v[32];
#pragma unroll
        for (int c = 0; c < 32; ++c) v[c] = A[i * LD + o + c];
#pragma unroll
        for (int c = 0; c < 32; ++c) {
          T acc = v[c];
          for (int k = 0; k < c; ++k) acc -= v[k] * Tb[c * 33 + k];
          v[c] = acc * Tb[c * 33 + 32];
        }
#pragma unroll
        for (int c = 0; c < 32; ++c) A[i * LD + o + c] = v[c];
      }
      __syncthreads();
      const int nt = rows / 4;
      const int ntile = nt * (nt + 1) / 2;
      for (int tix = tid; tix < ntile; tix += 256) {
        int ti = (int)((sqrtf(8.f * (float)tix + 1.f) - 1.f) * 0.5f);
        while ((ti + 1) * (ti + 2) / 2 <= tix) ++ti;
        while (ti * (ti + 1) / 2 > tix) --ti;
        const int tj = tix - ti * (ti + 1) / 2;
        const int gi = o + 32 + ti * 4, gj = o + 32 + tj * 4;
        T acc[4][4];
#pragma unroll
        for (int r = 0; r < 4; ++r)
#pragma unroll
          for (int c = 0; c < 4; ++c) acc[r][c] = (T)0;
        for (int k = 0; k < 32; ++k) {
          T a[4], b[4];
#pragma unroll
          for (int r = 0; r < 4; ++r) a[r] = A[(gi + r) * LD + o + k];
#pragma unroll
          for (int c = 0; c < 4; ++c) b[c] = A[(gj + c) * LD + o + k];
#pragma unroll
          for (int r = 0; r < 4; ++r)
#pragma unroll
            for (int c = 0; c < 4; ++c) acc[r][c] += a[r] * b[c];
        }
#pragma unroll
        for (int r = 0; r < 4; ++r)
#pragma unroll
          for (int c = 0; c < 4; ++c)
            A[(gi + r) * LD + (gj + c)] -= acc[r][c];
      }
      __syncthreads();
    }
  }
  {
    const int wv = tid >> 6, lane = tid & 63;
    if (wv < 3 && lane < 32) {
      const int o = wv * 32, c = lane;
      T* V = V3 + wv * 32 * 33;
      V[c * 33 + c] = rd[o + c];
      for (int r = c + 1; r < 32; ++r) {
        T acc = (T)0;
        for (int k = c; k < r; ++k)
          acc += A[(o + r) * LD + (o + k)] * V[k * 33 + c];
        V[r * 33 + c] = -acc * rd[o + r];
      }
      for (int r = 0; r < 32; ++r)
        W[(o + r) * LD + (o + c)] = (r < c) ? (T)0 : V[r * 33 + c];
    }
  }
  __syncthreads();
  T* L10 = A + 32 * LD + 0;
  T* L20 = A + 64 * LD + 0;
  T* L21 = A + 64 * LD + 32;
  T* W00 = W + 0;
  T* W10 = W + 32 * LD + 0;
  T* W11 = W + 32 * LD + 32;
  T* W20 = W + 64 * LD + 0;
  T* W21 = W + 64 * LD + 32;
  T* W22 = W + 64 * LD + 64;
  gemm32<T, false>(Tb, L10, W00, LD, LD, 33, tid); __syncthreads();
  gemm32_neg<T>(W10, W11, Tb, LD, 33, LD, tid);    __syncthreads();
  gemm32<T, false>(Tb, L20, W00, LD, LD, 33, tid); __syncthreads();
  gemm32<T, true>(Tb, L21, W10, LD, LD, 33, tid);  __syncthreads();
  gemm32_neg<T>(W20, W22, Tb, LD, 33, LD, tid);    __syncthreads();
  gemm32<T, false>(Tb, L21, W11, LD, LD, 33, tid); __syncthreads();
  gemm32_neg<T>(W21, W22, Tb, LD, 33, LD, tid);    __syncthreads();
}

// ---------------------------------------------------------------- S1: weights
__global__ __launch_bounds__(256) void k_weights(
    const float* __restrict__ Yraw, const float* __restrict__ kern,
    const float* __restrict__ wproj, float* __restrict__ WA,
    float* __restrict__ WB, float* __restrict__ Yt) {
  __shared__ float sk[NTAU * NSUB];
  __shared__ float sp[NSUB * NL];
  const int tid = threadIdx.x;
  if (tid < NTAU * NSUB) sk[tid] = kern[tid];
  if (tid < NSUB * NL)   sp[tid] = wproj[tid];
  __syncthreads();
  const int g = blockIdx.x * 256 + tid;            // g = (m*Tt + t)*Nn + n
  if (g >= Mb * Tt * Nn) return;
  const int n  = g % Nn;
  const int mt = g / Nn;
  const int t  = mt % Tt;
  const int m  = mt / Tt;
  const float* yr = Yraw + ((size_t)m * Nn + n) * NTF + 30 + t;
  float ya[NTAU + 1];
#pragma unroll
  for (int j = 0; j <= NTAU; ++j) ya[j] = yr[j];
  float gs[NSUB];
#pragma unroll
  for (int s = 0; s < NSUB; ++s) {
    float acc = 0.f;
#pragma unroll
    for (int j = 0; j < NTAU; ++j) acc += ya[j] * sk[(NTAU - 1 - j) * NSUB + s];
    gs[s] = (fabsf(acc) < 1e-5f) ? 0.f : acc;      // reference threshold
  }
  float w[NL];
#pragma unroll
  for (int l = 0; l < NL; ++l) {
    float acc = 0.f;
#pragma unroll
    for (int s = 0; s < NSUB; ++s) acc += gs[s] * sp[s * NL + l];
    w[l] = acc;
  }
  float4* wa4 = reinterpret_cast<float4*>(WA + (size_t)g * NL);
  wa4[0] = make_float4(w[0], w[1], w[2], w[3]);
  wa4[1] = make_float4(w[4], w[5], w[6], w[7]);
#pragma unroll
  for (int l = 0; l < NL; ++l)
    WB[(((size_t)m * NL + l) * Tt + t) * Nn + n] = w[l];
  Yt[g] = ya[NTAU];
}

// ---- S2: fixed-pivot fp64 Cholesky of K -> Ccm (col-major), Cg, dh0 --------
__global__ __launch_bounds__(320) void k_pchol(
    const float* __restrict__ K, double* __restrict__ Ccm,
    float* __restrict__ Cg, float* __restrict__ dh0) {
  __shared__ double Cp[R_];
  __shared__ double rho_s;
  const int t = threadIdx.x;
  for (int k = 0; k < R_; ++k) {
    const int p = (k * 103) % Tt;
    if (t < k) Cp[t] = Ccm[(size_t)t * TP + p];
    __syncthreads();
    double acc = 0.0;
    if (t < Tt) {
      for (int j = 0; j < k; ++j)
        acc += Ccm[(size_t)j * TP + t] * Cp[j];
    }
    if (t == p) rho_s = (double)K[(size_t)p * Tt + p] - acc;
    __syncthreads();
    const double rho = rho_s;
    double cv = 0.0;
    if (rho > 1e-12 && t < Tt)
      cv = ((double)K[(size_t)p * Tt + t] - acc) / sqrt(rho);
    Ccm[(size_t)k * TP + t] = (t < Tt) ? cv : 0.0;
    __syncthreads();
  }
  // Cg row-major [CROWS][97] fp32 (zero-padded rows/col)
  for (int e = t; e < CROWS * 97; e += 320) {
    const int r = e / 97, c = e - r * 97;
    Cg[e] = (r < Tt && c < R_) ? (float)Ccm[(size_t)c * TP + r] : 0.f;
  }
  if (t < TP) {
    double s = (t < Tt) ? (double)EPS : 0.0;
    if (t < Tt)
      for (int j = 0; j < R_; ++j) { const double v = Ccm[(size_t)j * TP + t]; s += v * v; }
    dh0[t] = (float)s;
  }
}

// ---------------- S2b: R64 = eps*I + C32^T C32 (fp64) -----------------------
__global__ __launch_bounds__(256) void k_rmul(
    const float* __restrict__ Cg, double* __restrict__ R64) {
  const int e = blockIdx.x * 256 + threadIdx.x;
  if (e >= R_ * R_) return;
  const int i = e / R_, j = e - i * R_;
  double acc = (i == j) ? 0.001 : 0.0;
  for (int r = 0; r < Tt; ++r)
    acc += (double)Cg[(size_t)r * 97 + i] * (double)Cg[(size_t)r * 97 + j];
  R64[e] = acc;
}

// --------------- S3a: chol96+trtri96 of R (fp64), W -> global ---------------
__global__ __launch_bounds__(256) void k_qchol(
    const double* __restrict__ R64, double* __restrict__ W64) {
  __shared__ double A[R_ * (R_ + 1)];
  __shared__ double Tb[32 * 33];
  __shared__ double rd[R_];
  __shared__ double V3[3 * 32 * 33];
  const int tid = threadIdx.x;
  for (int e = tid; e < R_ * R_; e += 256) {
    const int i = e / R_, j = e - i * R_;
    A[i * 97 + j] = R64[e];
  }
  __syncthreads();
  chol96_trtri96<double>(A, W64, Tb, rd, V3, tid);
}

// --------------- S3b: Q64 = W^T W (fp64) ------------------------------------
__global__ __launch_bounds__(256) void k_qmul(
    const double* __restrict__ W64, double* __restrict__ Qg) {
  const int e = blockIdx.x * 256 + threadIdx.x;
  if (e >= R_ * R_) return;
  const int i = e / R_, j = e - i * R_;
  const int k0 = (i > j) ? i : j;
  double acc = 0.0;
  for (int k = k0; k < R_; ++k) acc += W64[k * 97 + i] * W64[k * 97 + j];
  Qg[e] = acc;
}

// ---------------------------------------------------------------- S4: init
__global__ __launch_bounds__(256) void k_init(
    const float* __restrict__ dh0, float* __restrict__ mu, float* __restrict__ dh) {
  const int g = blockIdx.x * 256 + threadIdx.x;
  if (g >= Mb * Tt * NL) return;
  mu[g] = 0.f;
  dh[g] = dh0[(g / NL) % Tt];
}

// ---------------------------------------------------------------- I1: lambda
__global__ __launch_bounds__(256) void k_lambda(
    const float* __restrict__ WA, const float* __restrict__ mu,
    const float* __restrict__ dh, const float* __restrict__ biasp,
    float* __restrict__ lam) {
  const int g = blockIdx.x * 256 + threadIdx.x;
  if (g >= Mb * Tt * Nn) return;
  const int mt = g / Nn;
  const float b = biasp[0];
  const float4* wa = reinterpret_cast<const float4*>(WA + (size_t)g * NL);
  const float4* mp = reinterpret_cast<const float4*>(mu + (size_t)mt * NL);
  const float4* dp = reinterpret_cast<const float4*>(dh + (size_t)mt * NL);
  const float4 w0 = wa[0], w1 = wa[1];
  const float4 m0 = mp[0], m1 = mp[1];
  const float4 h0 = dp[0], h1 = dp[1];
  float e = b;
  e += w0.x * (m0.x + 0.5f * w0.x * h0.x);
  e += w0.y * (m0.y + 0.5f * w0.y * h0.y);
  e += w0.z * (m0.z + 0.5f * w0.z * h0.z);
  e += w0.w * (m0.w + 0.5f * w0.w * h0.w);
  e += w1.x * (m1.x + 0.5f * w1.x * h1.x);
  e += w1.y * (m1.y + 0.5f * w1.y * h1.y);
  e += w1.z * (m1.z + 0.5f * w1.z * h1.z);
  e += w1.w * (m1.w + 0.5f * w1.w * h1.w);
  lam[g] = expf(e);
}

// --------------------------------------- I2: g1 = W^T(Y-lam), d = (W^2)^T lam
__global__ __launch_bounds__(320) void k_gd(
    const float* __restrict__ WB, const float* __restrict__ Yt,
    const float* __restrict__ lam, float* __restrict__ g1, float* __restrict__ dvec) {
  const int ml = blockIdx.x;
  const int m = ml / NL;
  const int t = threadIdx.x;
  float ga = 0.f, dd = 0.f;
  if (t < Tt) {
    const float4* wb = reinterpret_cast<const float4*>(WB + ((size_t)ml * Tt + t) * Nn);
    const float4* yt = reinterpret_cast<const float4*>(Yt + ((size_t)m * Tt + t) * Nn);
    const float4* la = reinterpret_cast<const float4*>(lam + ((size_t)m * Tt + t) * Nn);
    for (int q = 0; q < Nn / 4; ++q) {
      const float4 w = wb[q], y = yt[q], v = la[q];
      ga += w.x * (y.x - v.x) + w.y * (y.y - v.y) + w.z * (y.z - v.z) + w.w * (y.w - v.w);
      dd += w.x * w.x * v.x + w.y * w.y * v.y + w.z * w.z * v.z + w.w * w.w * v.w;
    }
  }
  g1[(size_t)ml * TP + t]   = (t < Tt) ? ga : 0.f;
  dvec[(size_t)ml * TP + t] = (t < Tt) ? dd : 0.f;
}

// ------- I3: per-system vectors: s, delta; p = C^T mu; q = Q p; grad; u -----
__global__ __launch_bounds__(320) void k_pre(
    const float* __restrict__ Cg, const double* __restrict__ Qg,
    const float* __restrict__ g1, const float* __restrict__ dvec,
    const float* __restrict__ mug, float* __restrict__ gradb,
    float* __restrict__ svb, float* __restrict__ delb, float* __restrict__ ub) {
  const int ml = blockIdx.x;
  const int mt = ml / NL, lat = ml % NL;
  const int tid = threadIdx.x;                     // 0..319
  __shared__ float Cb[32 * 97];
  __shared__ float muv[TP], gv[TP], sv[TP], sg[TP];
  __shared__ double pv[R_], qv[R_];
  {
    float m_ = 0.f, g_ = 0.f, d_ = 0.f;
    if (tid < Tt) {
      m_ = mug[((size_t)mt * Tt + tid) * NL + lat];
      g_ = g1[(size_t)ml * TP + tid];
      d_ = dvec[(size_t)ml * TP + tid];
    }
    muv[tid] = m_; gv[tid] = g_;
    const float s = 1.f / (1.f + EPS * d_);
    sv[tid] = s;
    svb[(size_t)ml * TP + tid]  = s;
    delb[(size_t)ml * TP + tid] = d_ * s;
  }
  __syncthreads();
  // p = C^T mu (fp64 accum)
  double run_p = 0.0;
  for (int b = 0; b < 10; ++b) {
    for (int e = tid; e < 32 * 97; e += 320)
      Cb[e] = Cg[(size_t)(b * 32) * 97 + e];
    __syncthreads();
    if (tid < R_)
      for (int rr = 0; rr < 32; ++rr)
        run_p += (double)Cb[rr * 97 + tid] * (double)muv[b * 32 + rr];
    __syncthreads();
  }
  if (tid < R_) pv[tid] = run_p;
  __syncthreads();
  // q = Q64 p
  if (tid < R_) {
    double acc = 0.0;
    for (int j = 0; j < R_; ++j) acc += Qg[(size_t)j * R_ + tid] * pv[j];
    qv[tid] = acc;
  }
  __syncthreads();
  // grad = g1 - 1000*(mu - C q)  [fp64 inner];  u = C^T (s*grad)
  float run_u = 0.f;
  for (int b = 0; b < 10; ++b) {
    for (int e = tid; e < 32 * 97; e += 320)
      Cb[e] = Cg[(size_t)(b * 32) * 97 + e];
    __syncthreads();
    if (tid < 32) {
      const int t = b * 32 + tid;
      double cq = 0.0;
      for (int k = 0; k < R_; ++k) cq += (double)Cb[tid * 97 + k] * qv[k];
      const double gnew = (double)gv[t] - 1000.0 * ((double)muv[t] - cq);
      gv[t] = (float)gnew;
      sg[t] = sv[t] * gv[t];
    }
    __syncthreads();
    if (tid < R_)
      for (int rr = 0; rr < 32; ++rr)
        run_u += Cb[rr * 97 + tid] * sg[b * 32 + rr];
    __syncthreads();
  }
  gradb[(size_t)ml * TP + tid] = gv[tid];
  if (tid < R_) ub[(size_t)ml * R_ + tid] = run_u;
}

// ---- I4: Mhat partial = C^T diag(delta) C over a 160-row t-half ------------
// 256 WGs = (system, half). 6x6 register tiles, float2 LDS reads, symmetric-
// half compute with mirror writes. Output Mh2[bid][96][96] (no +I here).
__global__ __launch_bounds__(256) void k_mhat(
    const float* __restrict__ Cg, const float* __restrict__ delb,
    float* __restrict__ Mh2) {
  const int s = blockIdx.x >> 1, th = blockIdx.x & 1;
  const int tid = threadIdx.x;
  __shared__ float Cb[160 * 98];      // stride 98: float2-aligned, 2-way banks
  __shared__ float dl[160];
  {
    const float* Cs = Cg + (size_t)(th * 160) * 97;
    for (int e = tid; e < 160 * 97; e += 256) {
      const int r = e / 97, c = e - r * 97;
      Cb[r * 98 + c] = Cs[e];
    }
    for (int e = tid; e < 160; e += 256)
      dl[e] = delb[(size_t)s * TP + th * 160 + e];
  }
  __syncthreads();
  const int a = tid & 15, b = tid >> 4;
  if (a < b) return;                  // tile covered by mirror (no syncs below)
  const int i0 = a * 6, j0 = b * 6;
  float acc[6][6];
#pragma unroll
  for (int r = 0; r < 6; ++r)
#pragma unroll
    for (int c = 0; c < 6; ++c) acc[r][c] = 0.f;
  for (int t = 0; t < 160; ++t) {
    const float w = dl[t];
    const float2 u0 = *reinterpret_cast<const float2*>(&Cb[t * 98 + i0]);
    const float2 u1 = *reinterpret_cast<const float2*>(&Cb[t * 98 + i0 + 2]);
    const float2 u2 = *reinterpret_cast<const float2*>(&Cb[t * 98 + i0 + 4]);
    const float2 v0 = *reinterpret_cast<const float2*>(&Cb[t * 98 + j0]);
    const float2 v1 = *reinterpret_cast<const float2*>(&Cb[t * 98 + j0 + 2]);
    const float2 v2 = *reinterpret_cast<const float2*>(&Cb[t * 98 + j0 + 4]);
    const float ua[6] = {u0.x * w, u0.y * w, u1.x * w, u1.y * w, u2.x * w, u2.y * w};
    const float vb[6] = {v0.x, v0.y, v1.x, v1.y, v2.x, v2.y};
#pragma unroll
    for (int r = 0; r < 6; ++r)
#pragma unroll
      for (int c = 0; c < 6; ++c) acc[r][c] += ua[r] * vb[c];
  }
  float* base = Mh2 + (size_t)blockIdx.x * (R_ * R_);
#pragma unroll
  for (int r = 0; r < 6; ++r)
#pragma unroll
    for (int c = 0; c < 6; ++c)
      base[(i0 + r) * R_ + (j0 + c)] = acc[r][c];
  if (a > b) {
#pragma unroll
    for (int r = 0; r < 6; ++r)
#pragma unroll
      for (int c = 0; c < 6; ++c)
        base[(j0 + c) * R_ + (i0 + r)] = acc[r][c];
  }
}

// ---- I5: Mhat = I + sum halves; chol96 + trtri96; y = W^T(W u); W,y out ----
__global__ __launch_bounds__(256) void k_cholM(
    const float* __restrict__ Mh2, const float* __restrict__ ub,
    float* __restrict__ Wg, float* __restrict__ yb) {
  const int s = blockIdx.x;
  const int tid = threadIdx.x;
  __shared__ float A[R_ * 97];
  __shared__ float W[R_ * 97];
  __shared__ float Tb[32 * 33];
  __shared__ float rd[R_];
  __shared__ float V3[3 * 32 * 33];
  __shared__ float uvs[R_], t1[R_];
  const float* M0 = Mh2 + (size_t)(2 * s) * (R_ * R_);
  const float* M1 = Mh2 + (size_t)(2 * s + 1) * (R_ * R_);
  for (int e = tid; e < R_ * R_; e += 256) {
    const int i = e / R_, j = e - i * R_;
    A[i * 97 + j] = M0[e] + M1[e] + ((i == j) ? 1.f : 0.f);
  }
  for (int e = tid; e < R_ * 97; e += 256) W[e] = 0.f;  // block-upper must be 0
  if (tid < R_) uvs[tid] = ub[(size_t)s * R_ + tid];
  __syncthreads();
  chol96_trtri96<float>(A, W, Tb, rd, V3, tid);
  if (tid < R_) {
    float acc = 0.f;
    for (int j = 0; j <= tid; ++j) acc += W[tid * 97 + j] * uvs[j];
    t1[tid] = acc;
  }
  __syncthreads();
  if (tid < R_) {
    float acc = 0.f;
    for (int i = tid; i < R_; ++i) acc += W[i * 97 + tid] * t1[i];
    yb[(size_t)s * R_ + tid] = acc;
  }
  float* Wo = Wg + (size_t)s * R_ * 97;
  for (int e = tid; e < R_ * 97; e += 256) Wo[e] = W[e];
}

// ---- I6: X = C W^T (6x6 tiles, triangular kmax) -> jsq -> dh, mu update ----
// 512 WGs = (system, t-block of 96). LDS: W + Cb (stride 98) = 75.3KB -> 2/CU.
__global__ __launch_bounds__(256) void k_fin(
    const float* __restrict__ Cg, const float* __restrict__ Wg,
    const float* __restrict__ yb, const float* __restrict__ gradb,
    const float* __restrict__ svb, float* __restrict__ mug,
    float* __restrict__ dhg) {
  const int bid = blockIdx.x;
  const int ml = bid >> 2, blk = bid & 3;
  const int mt = ml / NL, lat = ml % NL;
  const int tid = threadIdx.x;
  __shared__ float Wf[R_ * 98];
  __shared__ float Cb[R_ * 98];
  {
    const float* Ws = Wg + (size_t)ml * R_ * 97;
    for (int e = tid; e < R_ * 97; e += 256) {
      const int r = e / 97, c = e - r * 97;
      Wf[r * 98 + c] = Ws[e];
    }
    const float* Cs = Cg + (size_t)(blk * 96) * 97;
    for (int e = tid; e < 96 * 97; e += 256) {
      const int r = e / 97, c = e - r * 97;
      Cb[r * 98 + c] = Cs[e];
    }
  }
  __syncthreads();
  const int tg = tid & 15, jg = tid >> 4;
  const int t0 = tg * 6, j0 = jg * 6;
  float acc[6][6];
#pragma unroll
  for (int r = 0; r < 6; ++r)
#pragma unroll
    for (int c = 0; c < 6; ++c) acc[r][c] = 0.f;
  const int kmax = j0 + 6;            // W rows j0..j0+5 have zeros for k > row
  for (int k = 0; k < kmax; k += 2) {
    float2 cv[6], wv[6];
#pragma unroll
    for (int r = 0; r < 6; ++r) {
      cv[r] = *reinterpret_cast<const float2*>(&Cb[(t0 + r) * 98 + k]);
      wv[r] = *reinterpret_cast<const float2*>(&Wf[(j0 + r) * 98 + k]);
    }
#pragma unroll
    for (int r = 0; r < 6; ++r)
#pragma unroll
      for (int c = 0; c < 6; ++c)
        acc[r][c] += cv[r].x * wv[c].x + cv[r].y * wv[c].y;
  }
  float jp[6];
#pragma unroll
  for (int r = 0; r < 6; ++r) {
    float s = 0.f;
#pragma unroll
    for (int c = 0; c < 6; ++c) s += acc[r][c] * acc[r][c];
    jp[r] = s;
  }
  __syncthreads();
  // reuse Wf region: red[96][17] + yv[96]
  float* red = Wf;
  float* yv  = Wf + 96 * 17;
#pragma unroll
  for (int r = 0; r < 6; ++r) red[(t0 + r) * 17 + jg] = jp[r];
  if (tid < R_) yv[tid] = yb[(size_t)ml * R_ + tid];
  __syncthreads();
  if (tid < 96) {
    const int t = blk * 96 + tid;
    float S = 0.f;
#pragma unroll
    for (int q = 0; q < 16; ++q) S += red[tid * 17 + q];
    float cy = 0.f;
    for (int k = 0; k < R_; ++k) cy += Cb[tid * 98 + k] * yv[k];
    if (t < Tt) {
      const float s = svb[(size_t)ml * TP + t];
      const float g = gradb[(size_t)ml * TP + t];
      const size_t idx = ((size_t)mt * Tt + t) * NL + lat;
      const float x = EPS * s * g + s * cy;
      mug[idx] = mug[idx] + 0.5f * x;               // LR = 0.5
      dhg[idx] = -(EPS * s + s * s * S);
    }
  }
}

// ---------------------------------------------------------------- F1: output
__global__ __launch_bounds__(256) void k_out(
    const float* __restrict__ mu, float* __restrict__ out) {
  const int g = blockIdx.x * 256 + threadIdx.x;   // g = (m*NL + l)*Tt + t
  if (g >= Mb * NL * Tt) return;
  const int t = g % Tt;
  const int ml = g / Tt;
  const int m = ml / NL, l = ml % NL;
  out[g] = mu[((size_t)m * Tt + t) * NL + l];
}

// ------------------------------------------------------------------- launcher
extern "C" void kernel_launch(void* const* d_in, const int* in_sizes, int n_in,
                              void* d_out, int out_size, void* d_ws, size_t ws_size,
                              hipStream_t stream) {
  (void)in_sizes; (void)n_in; (void)out_size;
  const float* Yraw  = (const float*)d_in[0];
  const float* kern  = (const float*)d_in[1];
  const float* wproj = (const float*)d_in[2];
  const float* K     = (const float*)d_in[3];
  const float* biasp = (const float*)d_in[4];
  float* out = (float*)d_out;

  char* base = (char*)d_ws;
  size_t off = 0;
  auto alloc = [&](size_t bytes) -> void* {
    void* p = base + off;
    off += (bytes + 511) & ~(size_t)511;
    return p;
  };
  float*  WA    = (float*) alloc((size_t)Mb * Tt * Nn * NL * 4);
  float*  WB    = (float*) alloc((size_t)Mb * Tt * Nn * NL * 4);
  float*  Yt    = (float*) alloc((size_t)Mb * Tt * Nn * 4);
  float*  lam   = (float*) alloc((size_t)Mb * Tt * Nn * 4);
  float*  mu    = (float*) alloc((size_t)Mb * Tt * NL * 4);
  float*  dh    = (float*) alloc((size_t)Mb * Tt * NL * 4);
  float*  g1    = (float*) alloc((size_t)ML * TP * 4);
  float*  dvec  = (float*) alloc((size_t)ML * TP * 4);
  float*  gradb = (float*) alloc((size_t)ML * TP * 4);
  float*  svb   = (float*) alloc((size_t)ML * TP * 4);
  float*  delb  = (float*) alloc((size_t)ML * TP * 4);
  float*  ub    = (float*) alloc((size_t)ML * R_ * 4);
  float*  yb    = (float*) alloc((size_t)ML * R_ * 4);
  float*  Cg    = (float*) alloc((size_t)CROWS * 97 * 4);
  double* Ccm   = (double*)alloc((size_t)R_ * TP * 8);
  double* Q64   = (double*)alloc((size_t)R_ * R_ * 8);
  double* R64   = (double*)alloc((size_t)R_ * R_ * 8);
  double* W64   = (double*)alloc((size_t)R_ * 97 * 8);
  float*  Mh2   = (float*) alloc((size_t)ML * 2 * R_ * R_ * 4);
  float*  Wg    = (float*) alloc((size_t)ML * R_ * 97 * 4);
  float*  dh0   = (float*) alloc((size_t)TP * 4);
  if (off > ws_size) return;

  const int gMTN = (Mb * Tt * Nn) / 256;       // 1800
  const int gMTL = (Mb * Tt * NL + 255) / 256; // 150
  const int gRR  = (R_ * R_ + 255) / 256;      // 36

  k_weights<<<gMTN, 256, 0, stream>>>(Yraw, kern, wproj, WA, WB, Yt);
  k_pchol<<<1, 320, 0, stream>>>(K, Ccm, Cg, dh0);
  k_rmul<<<gRR, 256, 0, stream>>>(Cg, R64);
  k_qchol<<<1, 256, 0, stream>>>(R64, W64);
  k_qmul<<<gRR, 256, 0, stream>>>(W64, Q64);
  k_init<<<gMTL, 256, 0, stream>>>(dh0, mu, dh);

  for (int it = 0; it < 5; ++it) {
    k_lambda<<<gMTN, 256, 0, stream>>>(WA, mu, dh, biasp, lam);
    k_gd<<<ML, 320, 0, stream>>>(WB, Yt, lam, g1, dvec);
    k_pre<<<ML, 320, 0, stream>>>(Cg, Q64, g1, dvec, mu, gradb, svb, delb, ub);
    k_mhat<<<ML * 2, 256, 0, stream>>>(Cg, delb, Mh2);
    k_cholM<<<ML, 256, 0, stream>>>(Mh2, ub, Wg, yb);
    k_fin<<<ML * 4, 256, 0, stream>>>(Cg, Wg, yb, gradb, svb, mu, dh);
  }
  k_out<<<gMTL, 256, 0, stream>>>(mu, out);
}